// Round 6
// baseline (812.443 us; speedup 1.0000x reference)
//
#include <hip/hip_runtime.h>

typedef unsigned short u16;
typedef unsigned int u32;
typedef unsigned long long u64;
typedef __attribute__((ext_vector_type(8))) short short8;
typedef __attribute__((ext_vector_type(4))) float f32x4;

#define NB_ 32

static __device__ __forceinline__ f32x4 mfma16(short8 a, short8 b, f32x4 c) {
  return __builtin_amdgcn_mfma_f32_16x16x32_bf16(a, b, c, 0, 0, 0);
}

// split fp32 -> bf16 hi + bf16 lo  (x ~= hi + lo, residual ~2^-17 * |x|)
static __device__ __forceinline__ void split_bf16(float x, u16& hi, u16& lo) {
  unsigned u = __float_as_uint(x);
  unsigned r = (u + 0x7fffu + ((u >> 16) & 1u)) >> 16;
  hi = (u16)r;
  float fh = __uint_as_float(r << 16);
  float xl = x - fh;
  unsigned ul = __float_as_uint(xl);
  unsigned rl2 = (ul + 0x7fffu + ((ul >> 16) & 1u)) >> 16;
  lo = (u16)rl2;
}

// write-through publication store to the coherence point (proven r1-r5)
static __device__ __forceinline__ void astore(u32* p, u32 v) {
  __hip_atomic_store(p, v, __ATOMIC_RELAXED, __HIP_MEMORY_SCOPE_AGENT);
}
// coherent coalesced 16B load: bypass L1+L2, read at the coherence point
static __device__ __forceinline__ void cload16(uint4& d, const u32* p) {
  asm volatile("global_load_dwordx4 %0, %1, off sc0 sc1" : "=v"(d) : "v"(p));
}
static __device__ __forceinline__ void cwait() {
  asm volatile("s_waitcnt vmcnt(0)" ::: "memory");
  __builtin_amdgcn_sched_barrier(0);
}
static __device__ __forceinline__ void unpack8(const uint4& a, const uint4& b,
                                               short8& h, short8& l) {
  u32 wb[8] = {a.x, a.y, a.z, a.w, b.x, b.y, b.z, b.w};
  #pragma unroll
  for (int j = 0; j < 8; ++j) {
    h[j] = (short)(wb[j] & 0xffffu);
    l[j] = (short)(wb[j] >> 16);
  }
}
static __device__ __forceinline__ float unpack_hl(u32 pk) {
  return __uint_as_float((pk & 0xffffu) << 16) + __uint_as_float(pk & 0xffff0000u);
}
static __device__ __forceinline__ void vload8(const u32* p, short8& h, short8& l) {
  uint4 a = *(const uint4*)p;
  uint4 b = *(const uint4*)(p + 4);
  unpack8(a, b, h, l);
}

// ---------------- pooling: emb gather + mean over valid items ----------------
__global__ __launch_bounds__(128) void k_pool(const int* __restrict__ iv,
                                              const float* __restrict__ emb,
                                              u16* __restrict__ ebh, u16* __restrict__ ebl,
                                              float* __restrict__ cm) {
  int u = blockIdx.x;             // u = (s*2+t)*64+b
  int s = u >> 7;
  int t = (u >> 6) & 1;
  int b = u & 63;
  int d = threadIdx.x;
  const int ibase = ((t * 64 + b) * 30 + s) * 12;
  float sum = 0.f;
  int cnt = 0;
  for (int k = 0; k < 12; ++k) {
    int idx = iv[ibase + k];
    if (idx > 0) { cnt++; sum += emb[(size_t)idx * 128 + d]; }
  }
  float den = (cnt > 0) ? (float)cnt : 1.f;
  float v = sum / den;
  u16 hi, lo; split_bf16(v, hi, lo);
  ebh[(size_t)u * 128 + d] = hi;
  ebl[(size_t)u * 128 + d] = lo;
  if (d == 0) cm[u] = (cnt > 0) ? 1.f : 0.f;
}

// ---------------- weight swizzle into MFMA B-fragment layout ----------------
// B-frag (16x16x32): lane l holds B[k=(l>>4)*8+j][n=l&15], j=0..7
// NB=32 blocks: t1=blk>>4, hd1=(blk&15)*16 (16 task dims), hd2=blk*8 (8 meta dims)
// w1 : 32 blk * 48 units (unit=ks*3+nt; ks 0..7 WihH K=256, 8..15 Whh K=256; nt 0=r,1=z,2=n cols hd1..hd1+16)
// w1x: 32 blk * 12 units (ks 0..3 over K=128 x-part; same nt)
// w2 : 32 blk * 48 units (unit=ks*2+nt; ks 0..7 mWih own task, 8..15 other task, 16..23 mWhh;
//      nt0: c<8 r[hd2+c] else z[hd2+c-8]; nt1: c<8 n[hd2+c] else pad)
__global__ __launch_bounds__(256) void k_swz(const float* __restrict__ Wih,
                                             const float* __restrict__ Whh,
                                             const float* __restrict__ mWih,
                                             const float* __restrict__ mWhh,
                                             const float* __restrict__ Wnew,
                                             u16* __restrict__ w1h, u16* __restrict__ w1l,
                                             u16* __restrict__ w1xh, u16* __restrict__ w1xl,
                                             u16* __restrict__ w2h, u16* __restrict__ w2l,
                                             u16* __restrict__ wnh, u16* __restrict__ wnl) {
  int gu = blockIdx.x * 4 + (threadIdx.x >> 6);
  int lane = threadIdx.x & 63;
  int ko = (lane >> 4) * 8;
  int c = lane & 15;
  float src[8];
  #pragma unroll
  for (int j = 0; j < 8; ++j) src[j] = 0.f;
  u16 *dh, *dl; int off;
  if (gu < 1536) {                       // w1 (h parts)
    int blk = gu / 48, r = gu % 48, ks = r / 3, nt = r % 3;
    int t1 = blk >> 4, hd1 = (blk & 15) * 16;
    int gc = nt * 256 + hd1 + c;
    const float* wrow; int kk;
    if (ks < 8) { wrow = Wih + (size_t)(t1 * 768 + gc) * 384 + 128; kk = ks * 32 + ko; }
    else        { wrow = Whh + (size_t)(t1 * 768 + gc) * 256;       kk = (ks - 8) * 32 + ko; }
    #pragma unroll
    for (int j = 0; j < 8; ++j) src[j] = wrow[kk + j];
    dh = w1h; dl = w1l; off = gu * 512 + lane * 8;
  } else if (gu < 1920) {                // w1x (x part, K=128)
    int g = gu - 1536;
    int blk = g / 12, r = g % 12, ks = r / 3, nt = r % 3;
    int t1 = blk >> 4, hd1 = (blk & 15) * 16;
    int gc = nt * 256 + hd1 + c;
    const float* wrow = Wih + (size_t)(t1 * 768 + gc) * 384;
    int kk = ks * 32 + ko;
    #pragma unroll
    for (int j = 0; j < 8; ++j) src[j] = wrow[kk + j];
    dh = w1xh; dl = w1xl; off = g * 512 + lane * 8;
  } else if (gu < 3456) {                // w2
    int g = gu - 1920;
    int blk = g / 48, r = g % 48, ks = r / 2, nt = r % 2;
    int t1 = blk >> 4, hd2 = blk * 8;
    bool valid = true; int gc = 0;
    if (nt == 0) gc = (c < 8) ? (hd2 + c) : (256 + hd2 + (c - 8));
    else { if (c < 8) gc = 512 + hd2 + c; else valid = false; }
    if (valid) {
      if (ks < 16) {
        int kk = ((ks < 8) ? (t1 * 256 + ks * 32) : ((1 - t1) * 256 + (ks - 8) * 32)) + ko;
        #pragma unroll
        for (int j = 0; j < 8; ++j) src[j] = mWih[(size_t)gc * 512 + kk + j];
      } else {
        int kk = (ks - 16) * 32 + ko;
        #pragma unroll
        for (int j = 0; j < 8; ++j) src[j] = mWhh[(size_t)gc * 256 + kk + j];
      }
    }
    dh = w2h; dl = w2l; off = g * 512 + lane * 8;
  } else if (gu < 13504) {               // wN
    int g = gu - 3456;
    int gnt = g >> 3, ks = g & 7;
    int col = gnt * 16 + c;
    if (col < 20000) {
      int kk = ks * 32 + ko;
      #pragma unroll
      for (int j = 0; j < 8; ++j) src[j] = Wnew[(size_t)col * 256 + kk + j];
    }
    dh = wnh; dl = wnl; off = g * 512 + lane * 8;
  } else return;
  #pragma unroll
  for (int j = 0; j < 8; ++j) { u16 h, l; split_bf16(src[j], h, l); dh[off + j] = h; dl[off + j] = l; }
}

// ---------------- gi_x precompute: gi_x = x @ WihX^T (+bias folds) ----------------
// gix[blk][s][nt][64 rows][16]: nt0 r(+bih+bhh), nt1 z(+bih+bhh), nt2 n(+bih)
__global__ __launch_bounds__(256) void k_gix(const u16* __restrict__ ebh, const u16* __restrict__ ebl,
                                             const u16* __restrict__ w1xh, const u16* __restrict__ w1xl,
                                             const float* __restrict__ bih, const float* __restrict__ bhh,
                                             float* __restrict__ gix) {
  int blk = blockIdx.x;                  // 0..31
  int t1 = blk >> 4, hd1 = (blk & 15) * 16;
  int tid = threadIdx.x, lane = tid & 63, w = tid >> 6;
  int arow = w * 16 + (lane & 15);
  int ko = (lane >> 4) * 8;
  int cc = lane & 15;
  __shared__ u16 lwh[6144], lwl[6144];   // 12 units
  {
    const uint4* sh = (const uint4*)(w1xh + (size_t)blk * 12 * 512);
    const uint4* sl = (const uint4*)(w1xl + (size_t)blk * 12 * 512);
    uint4* dh = (uint4*)lwh; uint4* dl = (uint4*)lwl;
    for (int i = tid; i < 768; i += 256) { dh[i] = sh[i]; dl[i] = sl[i]; }
  }
  float b0 = bih[t1 * 768 + hd1 + cc] + bhh[t1 * 768 + hd1 + cc];
  float b1 = bih[t1 * 768 + 256 + hd1 + cc] + bhh[t1 * 768 + 256 + hd1 + cc];
  float b2 = bih[t1 * 768 + 512 + hd1 + cc];
  __syncthreads();
  for (int s = 0; s < 30; ++s) {
    f32x4 a3[3];
    #pragma unroll
    for (int i = 0; i < 3; ++i) a3[i] = (f32x4){0.f, 0.f, 0.f, 0.f};
    const u16* Xh = ebh + (size_t)((s * 2 + t1) * 64 + arow) * 128;
    const u16* Xl = ebl + (size_t)((s * 2 + t1) * 64 + arow) * 128;
    #pragma unroll
    for (int k = 0; k < 4; ++k) {
      short8 xh = *(const short8*)(Xh + k * 32 + ko);
      short8 xl = *(const short8*)(Xl + k * 32 + ko);
      #pragma unroll
      for (int nt = 0; nt < 3; ++nt) {
        int u = k * 3 + nt;
        short8 bh = *(const short8*)(lwh + u * 512 + lane * 8);
        short8 bl = *(const short8*)(lwl + u * 512 + lane * 8);
        a3[nt] = mfma16(xh, bh, a3[nt]);
        a3[nt] = mfma16(xl, bh, a3[nt]);
        a3[nt] = mfma16(xh, bl, a3[nt]);
      }
    }
    float* g = gix + (size_t)(blk * 30 + s) * 3072;
    #pragma unroll
    for (int i = 0; i < 4; ++i) {
      int r = w * 16 + (lane >> 4) * 4 + i;
      g[r * 16 + cc]        = a3[0][i] + b0;
      g[1024 + r * 16 + cc] = a3[1][i] + b1;
      g[2048 + r * 16 + cc] = a3[2][i] + b2;
    }
  }
}

// ---------------- persistent GRU recurrence (NB=32) ----------------
static __device__ __forceinline__ void gridbar(u32* slots, int blk, int& epoch) {
  __syncthreads();              // drains vmcnt: publication stores at coherence point
  ++epoch;
  int tid = threadIdx.x;
  if (tid == 0) astore(slots + blk, (u32)epoch);
  if (tid < NB_) {
    u32 v;
    for (;;) {
      asm volatile("global_load_dword %0, %1, off sc0 sc1\n\ts_waitcnt vmcnt(0)"
                   : "=v"(v) : "v"(slots + tid) : "memory");
      if ((int)v >= epoch) break;
      __builtin_amdgcn_s_sleep(1);
    }
  }
  __syncthreads();
}

// dynamic LDS (bytes): w1h 49152 | w1l 49152 | w2h 49152 | ls_rz 8192 | ls_gi 4096 | ls_gh 4096 = 163840
#define RNN_LDS 163840

__global__ __launch_bounds__(256, 1) void k_rnn(
    const u16* __restrict__ w1h, const u16* __restrict__ w1l,
    const u16* __restrict__ w2h, const u16* __restrict__ w2l,
    const float* __restrict__ gix,
    const float* __restrict__ bhh,
    const float* __restrict__ mbih, const float* __restrict__ mbhh,
    const float* __restrict__ cm,
    u32* __restrict__ hpk,       // packed (hi|lo<<16) task-h [31][2][64][256]
    u32* __restrict__ apk,       // packed (hi|lo<<16) meta-h [1920][256] (b*30+s)
    u32* slots) {
  extern __shared__ char smem[];
  u16* lw1h = (u16*)smem;
  u16* lw1l = (u16*)(smem + 49152);
  u16* lw2h = (u16*)(smem + 98304);
  float* ls_rz = (float*)(smem + 147456);  // [64][32]
  float* ls_gi = (float*)(smem + 155648);  // [64][16]
  float* ls_gh = (float*)(smem + 159744);  // [64][16]

  const int blk = blockIdx.x;    // 0..31
  const int tid = threadIdx.x;
  const int lane = tid & 63;
  const int w = tid >> 6;
  const int t1 = blk >> 4;
  const int hd1 = (blk & 15) * 16;
  const int hd2 = blk * 8;
  const int arow = w * 16 + (lane & 15);
  const int ko = (lane >> 4) * 8;
  const int cc = lane & 15;
  int epoch = 0;

  // one-time: weights -> LDS (w1 hi+lo, w2 hi; w2 lo streams from L2 per step)
  {
    const uint4* s1h = (const uint4*)(w1h + (size_t)blk * 48 * 512);
    const uint4* s1l = (const uint4*)(w1l + (size_t)blk * 48 * 512);
    const uint4* s2h = (const uint4*)(w2h + (size_t)blk * 48 * 512);
    uint4* d1h = (uint4*)lw1h; uint4* d1l = (uint4*)lw1l; uint4* d2h = (uint4*)lw2h;
    for (int i = tid; i < 3072; i += 256) { d1h[i] = s1h[i]; d1l[i] = s1l[i]; d2h[i] = s2h[i]; }
  }
  const u16* gw2l = w2l + (size_t)blk * 48 * 512;
  // per-thread constants
  float bhhn = bhh[t1 * 768 + 512 + hd1 + cc];
  float mrz_b = (cc < 8) ? (mbih[hd2 + cc] + mbhh[hd2 + cc])
                         : (mbih[256 + hd2 + (cc - 8)] + mbhh[256 + hd2 + (cc - 8)]);
  float mgi_b = (cc < 8) ? mbih[512 + hd2 + cc] : 0.f;
  float mgh_b = (cc < 8) ? mbhh[512 + hd2 + cc] : 0.f;

  // gi_x prefetch (s=0)
  float gq[12];
  {
    const float* g = gix + (size_t)(blk * 30) * 3072;
    #pragma unroll
    for (int i = 0; i < 4; ++i) {
      int r = w * 16 + (lane >> 4) * 4 + i;
      gq[i]     = g[r * 16 + cc];
      gq[4 + i] = g[1024 + r * 16 + cc];
      gq[8 + i] = g[2048 + r * 16 + cc];
    }
  }
  __syncthreads();

  short8 ah1[8], al1[8];   // apk[s-1] (G1; reused by m2)
  short8 xh2[8], xl2[8];   // own-task hpk[s] (loaded phase-2 of s-1; used by G2)
  float hold[4] = {0.f, 0.f, 0.f, 0.f};
  float hm[2] = {0.f, 0.f};

  for (int s = 0; s < 30; ++s) {
    // ---------- phase 1: task GRU slice ----------
    f32x4 a1[3], a2[3];
    #pragma unroll
    for (int i = 0; i < 3; ++i) {
      a1[i] = (f32x4){0.f, 0.f, 0.f, 0.f};
      a2[i] = (f32x4){0.f, 0.f, 0.f, 0.f};
    }
    if (s > 0) {
      uint4 ra[16];
      const u32* Ap = apk + (size_t)(arow * 30 + (s - 1)) * 256 + ko;
      #pragma unroll
      for (int k = 0; k < 8; ++k) {
        cload16(ra[2 * k],     Ap + k * 32);
        cload16(ra[2 * k + 1], Ap + k * 32 + 4);
      }
      __builtin_amdgcn_sched_barrier(0);
      // a2 (Whh @ h_task) on retained regs overlaps the coherent-load window
      #pragma unroll
      for (int k = 0; k < 8; ++k) {
        #pragma unroll
        for (int nt = 0; nt < 3; ++nt) {
          int u = (8 + k) * 3 + nt;
          short8 bh = *(const short8*)(lw1h + u * 512 + lane * 8);
          short8 bl = *(const short8*)(lw1l + u * 512 + lane * 8);
          a2[nt] = mfma16(xh2[k], bh, a2[nt]);
          a2[nt] = mfma16(xl2[k], bh, a2[nt]);
          a2[nt] = mfma16(xh2[k], bl, a2[nt]);
        }
      }
      cwait();
      #pragma unroll
      for (int k = 0; k < 8; ++k) {
        unpack8(ra[2 * k], ra[2 * k + 1], ah1[k], al1[k]);
        #pragma unroll
        for (int nt = 0; nt < 3; ++nt) {
          int u = k * 3 + nt;
          short8 bh = *(const short8*)(lw1h + u * 512 + lane * 8);
          short8 bl = *(const short8*)(lw1l + u * 512 + lane * 8);
          a1[nt] = mfma16(ah1[k], bh, a1[nt]);
          a1[nt] = mfma16(al1[k], bh, a1[nt]);
          a1[nt] = mfma16(ah1[k], bl, a1[nt]);
        }
      }
    }
    // gates -> LDS
    #pragma unroll
    for (int i = 0; i < 4; ++i) {
      int row = w * 16 + (lane >> 4) * 4 + i;
      ls_rz[row * 32 + cc]      = a1[0][i] + a2[0][i] + gq[i];
      ls_rz[row * 32 + 16 + cc] = a1[1][i] + a2[1][i] + gq[4 + i];
      ls_gi[row * 16 + cc]      = a1[2][i] + gq[8 + i];
      ls_gh[row * 16 + cc]      = a2[2][i] + bhhn;
    }
    __syncthreads();
    #pragma unroll
    for (int p = 0; p < 4; ++p) {
      int item = p * 256 + tid;
      int b = item >> 4, c = item & 15;
      float rv = ls_rz[b * 32 + c], zv = ls_rz[b * 32 + 16 + c];
      float gi = ls_gi[b * 16 + c], gh = ls_gh[b * 16 + c];
      float r = 1.f / (1.f + expf(-rv));
      float z = 1.f / (1.f + expf(-zv));
      float n = tanhf(gi + r * gh);
      float m = cm[(s * 2 + t1) * 64 + b];
      float hnew = (1.f - z) * n + z * hold[p];
      float hout = (m > 0.5f) ? hnew : hold[p];
      hold[p] = hout;
      int oo = (((s + 1) * 2 + t1) * 64 + b) * 256 + hd1 + c;
      u16 xh, xl; split_bf16(hout, xh, xl);
      astore(hpk + oo, (u32)xh | ((u32)xl << 16));
    }
    gridbar(slots, blk, epoch);

    // ---------- phase 2: meta GRU slice ----------
    f32x4 m1[2], m2[2];
    #pragma unroll
    for (int i = 0; i < 2; ++i) {
      m1[i] = (f32x4){0.f, 0.f, 0.f, 0.f};
      m2[i] = (f32x4){0.f, 0.f, 0.f, 0.f};
    }
    {
      uint4 rx[16], ry[16];
      const u32* Hp = hpk + (size_t)(((s + 1) * 2 + t1) * 64 + arow) * 256 + ko;
      const u32* Hq = hpk + (size_t)(((s + 1) * 2 + (1 - t1)) * 64 + arow) * 256 + ko;
      #pragma unroll
      for (int k = 0; k < 8; ++k) {
        cload16(rx[2 * k],     Hp + k * 32);
        cload16(rx[2 * k + 1], Hp + k * 32 + 4);
      }
      #pragma unroll
      for (int k = 0; k < 8; ++k) {
        cload16(ry[2 * k],     Hq + k * 32);
        cload16(ry[2 * k + 1], Hq + k * 32 + 4);
      }
      __builtin_amdgcn_sched_barrier(0);
      // gi_x prefetch for next step (cached; overlaps RTT)
      if (s < 29) {
        const float* g = gix + (size_t)(blk * 30 + s + 1) * 3072;
        #pragma unroll
        for (int i = 0; i < 4; ++i) {
          int r = w * 16 + (lane >> 4) * 4 + i;
          gq[i]     = g[r * 16 + cc];
          gq[4 + i] = g[1024 + r * 16 + cc];
          gq[8 + i] = g[2048 + r * 16 + cc];
        }
      }
      // m2 (mWhh @ h_meta) on retained regs overlaps the load window
      if (s > 0) {
        #pragma unroll
        for (int k = 0; k < 8; ++k) {
          #pragma unroll
          for (int nt = 0; nt < 2; ++nt) {
            int u = (16 + k) * 2 + nt;
            short8 bh = *(const short8*)(lw2h + u * 512 + lane * 8);
            short8 bl = *(const short8*)(gw2l + u * 512 + lane * 8);
            m2[nt] = mfma16(ah1[k], bh, m2[nt]);
            m2[nt] = mfma16(al1[k], bh, m2[nt]);
            m2[nt] = mfma16(ah1[k], bl, m2[nt]);
          }
        }
      }
      cwait();
      #pragma unroll
      for (int k = 0; k < 8; ++k) {
        unpack8(rx[2 * k], rx[2 * k + 1], xh2[k], xl2[k]);
        #pragma unroll
        for (int nt = 0; nt < 2; ++nt) {
          int u = k * 2 + nt;
          short8 bh = *(const short8*)(lw2h + u * 512 + lane * 8);
          short8 bl = *(const short8*)(gw2l + u * 512 + lane * 8);
          m1[nt] = mfma16(xh2[k], bh, m1[nt]);
          m1[nt] = mfma16(xl2[k], bh, m1[nt]);
          m1[nt] = mfma16(xh2[k], bl, m1[nt]);
        }
      }
      #pragma unroll
      for (int k = 0; k < 8; ++k) {
        short8 yh, yl;
        unpack8(ry[2 * k], ry[2 * k + 1], yh, yl);
        #pragma unroll
        for (int nt = 0; nt < 2; ++nt) {
          int u = (8 + k) * 2 + nt;
          short8 bh = *(const short8*)(lw2h + u * 512 + lane * 8);
          short8 bl = *(const short8*)(gw2l + u * 512 + lane * 8);
          m1[nt] = mfma16(yh, bh, m1[nt]);
          m1[nt] = mfma16(yl, bh, m1[nt]);
          m1[nt] = mfma16(yh, bl, m1[nt]);
        }
      }
    }
    #pragma unroll
    for (int i = 0; i < 4; ++i) {
      int row = w * 16 + (lane >> 4) * 4 + i;
      ls_rz[row * 32 + cc] = m1[0][i] + m2[0][i] + mrz_b;   // cols 0-7 r, 8-15 z
      if (cc < 8) {
        ls_gi[row * 16 + cc] = m1[1][i] + mgi_b;
        ls_gh[row * 16 + cc] = m2[1][i] + mgh_b;
      }
    }
    __syncthreads();
    #pragma unroll
    for (int p = 0; p < 2; ++p) {
      int item = p * 256 + tid;
      int b = item >> 3, c = item & 7;
      float rv = ls_rz[b * 32 + c], zv = ls_rz[b * 32 + 8 + c];
      float gi = ls_gi[b * 16 + c], gh = ls_gh[b * 16 + c];
      float r = 1.f / (1.f + expf(-rv));
      float z = 1.f / (1.f + expf(-zv));
      float n = tanhf(gi + r * gh);
      float hmnew = (1.f - z) * n + z * hm[p];
      hm[p] = hmnew;
      int ar = b * 30 + s;
      u16 xh, xl; split_bf16(hmnew, xh, xl);
      astore(apk + ar * 256 + hd2 + c, (u32)xh | ((u32)xl << 16));
    }
    gridbar(slots, blk, epoch);
  }
}

// ---------------- score_new GEMM: [1920,256] x [256,20000] (3-pass split bf16) ----------------
__global__ __launch_bounds__(256) void k_gnew(const u32* __restrict__ apk,
                                              const u16* __restrict__ wnh, const u16* __restrict__ wnl,
                                              const float* __restrict__ bnew,
                                              float* __restrict__ out) {
  int bid = blockIdx.x;
  int mb = bid / 157, nb = bid % 157;
  int tid = threadIdx.x, lane = tid & 63, w = tid >> 6;
  int ko = (lane >> 4) * 8;
  f32x4 acc[2][8];
  #pragma unroll
  for (int mi = 0; mi < 2; ++mi)
    #pragma unroll
    for (int nt = 0; nt < 8; ++nt) acc[mi][nt] = (f32x4){0.f, 0.f, 0.f, 0.f};
  #pragma unroll
  for (int ks = 0; ks < 8; ++ks) {
    short8 ah[2], al[2];
    #pragma unroll
    for (int mi = 0; mi < 2; ++mi) {
      int r = mb * 128 + (w * 2 + mi) * 16 + (lane & 15);
      vload8(apk + (size_t)r * 256 + ks * 32 + ko, ah[mi], al[mi]);
    }
    #pragma unroll
    for (int nt = 0; nt < 8; ++nt) {
      int un = (nb * 8 + nt) * 8 + ks;
      short8 bh = *(const short8*)(wnh + (size_t)un * 512 + lane * 8);
      short8 bl = *(const short8*)(wnl + (size_t)un * 512 + lane * 8);
      #pragma unroll
      for (int mi = 0; mi < 2; ++mi) {
        acc[mi][nt] = mfma16(ah[mi], bh, acc[mi][nt]);
        acc[mi][nt] = mfma16(al[mi], bh, acc[mi][nt]);
        acc[mi][nt] = mfma16(ah[mi], bl, acc[mi][nt]);
      }
    }
  }
  #pragma unroll
  for (int mi = 0; mi < 2; ++mi)
    #pragma unroll
    for (int nt = 0; nt < 8; ++nt) {
      int col = nb * 128 + nt * 16 + (lane & 15);
      if (col < 20000) {
        float bn = bnew[col];
        #pragma unroll
        for (int i = 0; i < 4; ++i) {
          int r = mb * 128 + (w * 2 + mi) * 16 + (lane >> 4) * 4 + i;
          out[(size_t)r * 20000 + col] = acc[mi][nt][i] + bn;
        }
      }
    }
}

// ---------------- copy scores: one block per (t,b,s); zero-fill + sparse ----------------
__global__ __launch_bounds__(256) void k_copy(const u32* __restrict__ hpk,
                                              const int* __restrict__ cv,
                                              const float* __restrict__ wc,
                                              const float* __restrict__ bc,
                                              float* __restrict__ out) {
  int u = blockIdx.x;                 // t*1920 + b*30 + s
  int t = u / 1920;
  int rem = u % 1920;
  int b = rem / 30, s = rem % 30;
  int tid = threadIdx.x, lane = tid & 63, w = tid >> 6;
  float* orow = out + (size_t)(1 + t) * 38400000 + (size_t)(b * 30 + s) * 20000;
  float4 z4 = {0.f, 0.f, 0.f, 0.f};
  for (int i = tid; i < 5000; i += 256) ((float4*)orow)[i] = z4;
  __shared__ float vals[20];
  const u32* hp = hpk + (size_t)(((s + 1) * 2 + t) * 64 + b) * 256;
  uint4 hq = *(const uint4*)(hp + lane * 4);
  float4 h4;
  h4.x = unpack_hl(hq.x); h4.y = unpack_hl(hq.y);
  h4.z = unpack_hl(hq.z); h4.w = unpack_hl(hq.w);
  int base = u * 20;
  for (int c = w; c < 20; c += 4) {
    int idx = cv[base + c];
    const float* wr = wc + ((size_t)t * 20000 + idx) * 256;
    float4 w4 = *(const float4*)(wr + lane * 4);
    float d = h4.x * w4.x + h4.y * w4.y + h4.z * w4.z + h4.w * w4.w;
    #pragma unroll
    for (int m = 32; m >= 1; m >>= 1) d += __shfl_xor(d, m, 64);
    if (lane == 0) vals[c] = d + bc[t * 20000 + idx];
  }
  __syncthreads();
  if (tid < 20) orow[cv[base + tid]] = vals[tid];
}

extern "C" void kernel_launch(void* const* d_in, const int* in_sizes, int n_in,
                              void* d_out, int out_size, void* d_ws, size_t ws_size,
                              hipStream_t stream) {
  const int* iv = (const int*)d_in[1];
  const int* cv = (const int*)d_in[2];
  const float* emb = (const float*)d_in[3];
  const float* Wih = (const float*)d_in[4];
  const float* Whh = (const float*)d_in[5];
  const float* bih = (const float*)d_in[6];
  const float* bhh = (const float*)d_in[7];
  const float* mWih = (const float*)d_in[8];
  const float* mWhh = (const float*)d_in[9];
  const float* mbih = (const float*)d_in[10];
  const float* mbhh = (const float*)d_in[11];
  const float* Wnew = (const float*)d_in[12];
  const float* bnew = (const float*)d_in[13];
  const float* Wcopy = (const float*)d_in[14];
  const float* bcopy = (const float*)d_in[15];
  float* out = (float*)d_out;
  char* ws = (char*)d_ws;

  size_t o = 0;
  auto take = [&](size_t sz) { size_t r = o; o += sz; return r; };
  size_t BAR  = take(256);
  size_t CM   = take(15360);
  size_t EBH  = take(983040);
  size_t EBL  = take(983040);
  size_t HPK  = take(4063232);    // packed bf16 hi|lo task-h [31][2][64][256] u32
  size_t APK  = take(1966080);    // packed bf16 hi|lo meta-h [1920][256] u32
  size_t GIX  = take(11796480);   // fp32 gi_x [32 blk][30][3][64][16]
  size_t W1H  = take(1572864);
  size_t W1L  = take(1572864);
  size_t W1XH = take(393216);
  size_t W1XL = take(393216);
  size_t W2H  = take(1572864);
  size_t W2L  = take(1572864);
  size_t WNH  = take(10289152);
  size_t WNL  = take(10289152);
  if (ws_size < o) return;   // insufficient workspace: fail loudly via absmax

  hipFuncSetAttribute(reinterpret_cast<const void*>(k_rnn),
                      hipFuncAttributeMaxDynamicSharedMemorySize, RNN_LDS);

  hipMemsetAsync(ws + BAR, 0, 256, stream);
  hipMemsetAsync(ws + HPK, 0, 131072, stream);

  k_pool<<<3840, 128, 0, stream>>>(iv, emb, (u16*)(ws + EBH), (u16*)(ws + EBL), (float*)(ws + CM));
  k_swz<<<3376, 256, 0, stream>>>(Wih, Whh, mWih, mWhh, Wnew,
                                  (u16*)(ws + W1H), (u16*)(ws + W1L),
                                  (u16*)(ws + W1XH), (u16*)(ws + W1XL),
                                  (u16*)(ws + W2H), (u16*)(ws + W2L),
                                  (u16*)(ws + WNH), (u16*)(ws + WNL));
  k_gix<<<32, 256, 0, stream>>>((const u16*)(ws + EBH), (const u16*)(ws + EBL),
                                (const u16*)(ws + W1XH), (const u16*)(ws + W1XL),
                                bih, bhh, (float*)(ws + GIX));
  k_rnn<<<NB_, 256, RNN_LDS, stream>>>((const u16*)(ws + W1H), (const u16*)(ws + W1L),
                                       (const u16*)(ws + W2H), (const u16*)(ws + W2L),
                                       (const float*)(ws + GIX), bhh, mbih, mbhh,
                                       (const float*)(ws + CM),
                                       (u32*)(ws + HPK), (u32*)(ws + APK),
                                       (u32*)(ws + BAR));
  k_gnew<<<2355, 256, 0, stream>>>((const u32*)(ws + APK),
                                   (const u16*)(ws + WNH), (const u16*)(ws + WNL),
                                   bnew, out);
  k_copy<<<3840, 256, 0, stream>>>((const u32*)(ws + HPK), cv, Wcopy, bcopy, out);
}

// Round 7
// 676.197 us; speedup vs baseline: 1.2015x; 1.2015x over previous
//
#include <hip/hip_runtime.h>

typedef unsigned short u16;
typedef unsigned int u32;
typedef unsigned long long u64;
typedef __attribute__((ext_vector_type(8))) short short8;
typedef __attribute__((ext_vector_type(4))) float f32x4;

#define NB_ 64
#define HELPERS_ 1152

static __device__ __forceinline__ f32x4 mfma16(short8 a, short8 b, f32x4 c) {
  return __builtin_amdgcn_mfma_f32_16x16x32_bf16(a, b, c, 0, 0, 0);
}

// split fp32 -> bf16 hi + bf16 lo  (x ~= hi + lo, residual ~2^-17 * |x|)
static __device__ __forceinline__ void split_bf16(float x, u16& hi, u16& lo) {
  unsigned u = __float_as_uint(x);
  unsigned r = (u + 0x7fffu + ((u >> 16) & 1u)) >> 16;
  hi = (u16)r;
  float fh = __uint_as_float(r << 16);
  float xl = x - fh;
  unsigned ul = __float_as_uint(xl);
  unsigned rl2 = (ul + 0x7fffu + ((ul >> 16) & 1u)) >> 16;
  lo = (u16)rl2;
}

// write-through publication store to the coherence point (proven r1-r6)
static __device__ __forceinline__ void astore(u32* p, u32 v) {
  __hip_atomic_store(p, v, __ATOMIC_RELAXED, __HIP_MEMORY_SCOPE_AGENT);
}
// coherent coalesced 16B load: bypass L1+L2, read at the coherence point
static __device__ __forceinline__ void cload16(uint4& d, const u32* p) {
  asm volatile("global_load_dwordx4 %0, %1, off sc0 sc1" : "=v"(d) : "v"(p));
}
static __device__ __forceinline__ void cwait() {
  asm volatile("s_waitcnt vmcnt(0)" ::: "memory");
  __builtin_amdgcn_sched_barrier(0);
}
static __device__ __forceinline__ void unpack8(const uint4& a, const uint4& b,
                                               short8& h, short8& l) {
  u32 wb[8] = {a.x, a.y, a.z, a.w, b.x, b.y, b.z, b.w};
  #pragma unroll
  for (int j = 0; j < 8; ++j) {
    h[j] = (short)(wb[j] & 0xffffu);
    l[j] = (short)(wb[j] >> 16);
  }
}
static __device__ __forceinline__ float unpack_hl(u32 pk) {
  return __uint_as_float((pk & 0xffffu) << 16) + __uint_as_float(pk & 0xffff0000u);
}
static __device__ __forceinline__ void vload8(const u32* p, short8& h, short8& l) {
  uint4 a = *(const uint4*)p;
  uint4 b = *(const uint4*)(p + 4);
  unpack8(a, b, h, l);
}

// ---------------- pooling: emb gather + mean over valid items ----------------
__global__ __launch_bounds__(128) void k_pool(const int* __restrict__ iv,
                                              const float* __restrict__ emb,
                                              u16* __restrict__ ebh, u16* __restrict__ ebl,
                                              float* __restrict__ cm) {
  int u = blockIdx.x;             // u = (s*2+t)*64+b
  int s = u >> 7;
  int t = (u >> 6) & 1;
  int b = u & 63;
  int d = threadIdx.x;
  const int ibase = ((t * 64 + b) * 30 + s) * 12;
  float sum = 0.f;
  int cnt = 0;
  for (int k = 0; k < 12; ++k) {
    int idx = iv[ibase + k];
    if (idx > 0) { cnt++; sum += emb[(size_t)idx * 128 + d]; }
  }
  float den = (cnt > 0) ? (float)cnt : 1.f;
  float v = sum / den;
  u16 hi, lo; split_bf16(v, hi, lo);
  ebh[(size_t)u * 128 + d] = hi;
  ebl[(size_t)u * 128 + d] = lo;
  if (d == 0) cm[u] = (cnt > 0) ? 1.f : 0.f;
}

// ---------------- weight swizzle into MFMA B-fragment layout ----------------
// B-frag (16x16x32): lane l holds B[k=(l>>4)*8+j][n=l&15], j=0..7
// w1: 64 blk * 20 ks * 2 nt; ks 0..7 WihH(K=256), 8..15 Whh(K=256), 16..19 WihX(K=128)
// w2: 64 blk * 24 ks; ks 0..7 mWih OWN task (t1=blk>>5), 8..15 mWih other task, 16..23 mWhh
__global__ __launch_bounds__(256) void k_swz(const float* __restrict__ Wih,
                                             const float* __restrict__ Whh,
                                             const float* __restrict__ mWih,
                                             const float* __restrict__ mWhh,
                                             const float* __restrict__ Wnew,
                                             u16* __restrict__ w1h, u16* __restrict__ w1l,
                                             u16* __restrict__ w2h, u16* __restrict__ w2l,
                                             u16* __restrict__ wnh, u16* __restrict__ wnl) {
  int gu = blockIdx.x * 4 + (threadIdx.x >> 6);
  int lane = threadIdx.x & 63;
  int ko = (lane >> 4) * 8;
  int cl = lane & 15;
  float src[8];
  if (gu < 2560) {
    int blk = gu / 40, r = gu % 40, ksIdx = r >> 1, nt = r & 1;
    int t = blk >> 5, hd0 = (blk & 31) * 8;
    int c = nt * 16 + cl;
    if (c < 24) {
      int gc = (c < 8) ? (hd0 + c) : (c < 16) ? (256 + hd0 + (c - 8)) : (512 + hd0 + (c - 16));
      const float* wrow; int kk;
      if (ksIdx < 8)       { wrow = Wih + (size_t)(t * 768 + gc) * 384 + 128; kk = ksIdx * 32 + ko; }
      else if (ksIdx < 16) { wrow = Whh + (size_t)(t * 768 + gc) * 256;       kk = (ksIdx - 8) * 32 + ko; }
      else                 { wrow = Wih + (size_t)(t * 768 + gc) * 384;       kk = (ksIdx - 16) * 32 + ko; }
      #pragma unroll
      for (int j = 0; j < 8; ++j) src[j] = wrow[kk + j];
    } else {
      #pragma unroll
      for (int j = 0; j < 8; ++j) src[j] = 0.f;
    }
    int off = gu * 512 + lane * 8;
    #pragma unroll
    for (int j = 0; j < 8; ++j) { u16 h, l; split_bf16(src[j], h, l); w1h[off + j] = h; w1l[off + j] = l; }
  } else if (gu < 4096) {
    int g2 = gu - 2560;
    int blk = g2 / 24, ksIdx = g2 % 24;
    int t1 = blk >> 5;
    int hd0 = blk * 4;
    int c = cl;
    if (c < 12) {
      int gc = (c < 4) ? (hd0 + c) : (c < 8) ? (256 + hd0 + (c - 4)) : (512 + hd0 + (c - 8));
      if (ksIdx < 16) {
        int chunk = (ksIdx < 8) ? (t1 * 8 + ksIdx) : ((1 - t1) * 8 + (ksIdx - 8));
        int kk = chunk * 32 + ko;
        #pragma unroll
        for (int j = 0; j < 8; ++j) src[j] = mWih[(size_t)gc * 512 + kk + j];
      } else {
        int kk = (ksIdx - 16) * 32 + ko;
        #pragma unroll
        for (int j = 0; j < 8; ++j) src[j] = mWhh[(size_t)gc * 256 + kk + j];
      }
    } else {
      #pragma unroll
      for (int j = 0; j < 8; ++j) src[j] = 0.f;
    }
    int off = g2 * 512 + lane * 8;
    #pragma unroll
    for (int j = 0; j < 8; ++j) { u16 h, l; split_bf16(src[j], h, l); w2h[off + j] = h; w2l[off + j] = l; }
  } else if (gu < 14144) {
    int g3 = gu - 4096;
    int gnt = g3 >> 3, ks = g3 & 7;
    int col = gnt * 16 + cl;
    if (col < 20000) {
      int kk = ks * 32 + ko;
      #pragma unroll
      for (int j = 0; j < 8; ++j) src[j] = Wnew[(size_t)col * 256 + kk + j];
    } else {
      #pragma unroll
      for (int j = 0; j < 8; ++j) src[j] = 0.f;
    }
    int off = g3 * 512 + lane * 8;
    #pragma unroll
    for (int j = 0; j < 8; ++j) { u16 h, l; split_bf16(src[j], h, l); wnh[off + j] = h; wnl[off + j] = l; }
  }
}

// ---------------- gi_x precompute: gi_x = x @ WihX^T (+bias folds) ----------------
// layout: gix[blk][s][row 0..63][32]: cols 0..15 = r,z (+bih+bhh), 16..23 = n (+bih)
__global__ __launch_bounds__(256) void k_gix(const u16* __restrict__ ebh, const u16* __restrict__ ebl,
                                             const u16* __restrict__ w1h, const u16* __restrict__ w1l,
                                             const float* __restrict__ bih, const float* __restrict__ bhh,
                                             float* __restrict__ gix) {
  int blk = blockIdx.x;
  int t1 = blk >> 5, hd1 = (blk & 31) * 8;
  int tid = threadIdx.x, lane = tid & 63, w = tid >> 6;
  int arow = w * 16 + (lane & 15);
  int ko = (lane >> 4) * 8;
  __shared__ u16 lwh[4096], lwl[4096];
  {
    const uint4* sh = (const uint4*)(w1h + ((size_t)blk * 40 + 32) * 512);
    const uint4* sl = (const uint4*)(w1l + ((size_t)blk * 40 + 32) * 512);
    uint4* dh = (uint4*)lwh; uint4* dl = (uint4*)lwl;
    for (int i = tid; i < 512; i += 256) { dh[i] = sh[i]; dl[i] = sl[i]; }
  }
  int c = lane & 15;
  float brz, bn = 0.f;
  {
    int gc = (c < 8) ? (hd1 + c) : (256 + hd1 + (c - 8));
    brz = bih[t1 * 768 + gc] + bhh[t1 * 768 + gc];
    if (c < 8) bn = bih[t1 * 768 + 512 + hd1 + c];
  }
  __syncthreads();
  for (int s = 0; s < 30; ++s) {
    f32x4 a3[2];
    a3[0] = (f32x4){0.f, 0.f, 0.f, 0.f};
    a3[1] = (f32x4){0.f, 0.f, 0.f, 0.f};
    const u16* Xh = ebh + (size_t)((s * 2 + t1) * 64 + arow) * 128;
    const u16* Xl = ebl + (size_t)((s * 2 + t1) * 64 + arow) * 128;
    #pragma unroll
    for (int k = 0; k < 4; ++k) {
      short8 xh = *(const short8*)(Xh + k * 32 + ko);
      short8 xl = *(const short8*)(Xl + k * 32 + ko);
      #pragma unroll
      for (int nt = 0; nt < 2; ++nt) {
        short8 bh = *(const short8*)(lwh + (k * 2 + nt) * 512 + lane * 8);
        short8 bl = *(const short8*)(lwl + (k * 2 + nt) * 512 + lane * 8);
        a3[nt] = mfma16(xh, bh, a3[nt]);
        a3[nt] = mfma16(xl, bh, a3[nt]);
        a3[nt] = mfma16(xh, bl, a3[nt]);
      }
    }
    float* grow = gix + (size_t)(blk * 30 + s) * 64 * 32;
    #pragma unroll
    for (int i = 0; i < 4; ++i) {
      int r = w * 16 + (lane >> 4) * 4 + i;
      grow[r * 32 + c] = a3[0][i] + brz;
      if (c < 8) grow[r * 32 + 16 + c] = a3[1][i] + bn;
    }
  }
}

// ---------------- persistent GRU recurrence ----------------
// Flag barrier: 64 contiguous u32 slots; arrival = relaxed agent store of epoch;
// wave-0 lanes poll one slot each via coherent (sc0 sc1) loads, tight loop.
static __device__ __forceinline__ void gridbar(u32* slots, int blk, int& epoch) {
  __syncthreads();              // drains vmcnt: publication stores at coherence point
  ++epoch;
  int tid = threadIdx.x;
  if (tid == 0) astore(slots + blk, (u32)epoch);
  if (tid < NB_) {
    u32 v;
    for (;;) {
      asm volatile("global_load_dword %0, %1, off sc0 sc1\n\ts_waitcnt vmcnt(0)"
                   : "=v"(v) : "v"(slots + tid) : "memory");
      if ((int)v >= epoch) break;
    }
  }
  __syncthreads();
}

// dynamic LDS layout (bytes):
//   [0)       w1h  32 units * 1024 = 32768
//   [32768)   w1l  32768
//   [65536)   w2h  24 units * 1024 = 24576
//   [90112)   w2l  24576            -> 114688
//   [114688)  ls_rz float[4][16][16] 4096
//   [118784)  ls_gi float[4][16][8]  2048
//   [120832)  ls_gh float[4][16][8]  2048
//   [122880)  ls_cm float[30][64]    7680  -> total 130560
#define RNN_LDS 130560

__global__ __launch_bounds__(256, 1) void k_rnn(
    const u16* __restrict__ w1h, const u16* __restrict__ w1l,
    const u16* __restrict__ w2h, const u16* __restrict__ w2l,
    const float* __restrict__ gix,
    const float* __restrict__ bhh,
    const float* __restrict__ mbih, const float* __restrict__ mbhh,
    const float* __restrict__ cm,
    u32* __restrict__ hpk,       // packed (hi|lo<<16) task-h   [31][2][64][256]
    u32* __restrict__ apk,       // packed (hi|lo<<16) meta-h   [1920][256] (b*30+s)
    u32* slots,
    float* __restrict__ zout) {  // sparse-score region to zero (helpers)
  // ---- helper blocks: zero the 307.2 MB copy-score region, then exit ----
  if (blockIdx.x >= NB_) {
    const size_t totalf4 = 19200000;   // 307,200,000 B / 16
    size_t idx = (size_t)(blockIdx.x - NB_) * 256 + threadIdx.x;
    size_t stride = (size_t)HELPERS_ * 256;
    float4 z4 = {0.f, 0.f, 0.f, 0.f};
    float4* zp = (float4*)zout;
    for (size_t i = idx; i < totalf4; i += stride) zp[i] = z4;
    return;
  }

  extern __shared__ char smem[];
  u16* lw1h = (u16*)smem;
  u16* lw1l = (u16*)(smem + 32768);
  u16* lw2h = (u16*)(smem + 65536);
  u16* lw2l = (u16*)(smem + 90112);
  float* ls_rz = (float*)(smem + 114688);
  float* ls_gi = (float*)(smem + 118784);
  float* ls_gh = (float*)(smem + 120832);
  float* ls_cm = (float*)(smem + 122880);

  const int blk = blockIdx.x;
  const int tid = threadIdx.x;
  const int lane = tid & 63;
  const int w = tid >> 6;
  const int t1 = blk >> 5;
  const int hd1 = (blk & 31) * 8;
  const int hd2 = blk * 4;
  const int arow = w * 16 + (lane & 15);
  const int ko = (lane >> 4) * 8;
  int epoch = 0;

  // one-time: weights -> LDS, cm -> LDS
  {
    const uint4* s1h = (const uint4*)(w1h + (size_t)blk * 40 * 512);
    const uint4* s1l = (const uint4*)(w1l + (size_t)blk * 40 * 512);
    uint4* d1h = (uint4*)lw1h; uint4* d1l = (uint4*)lw1l;
    for (int i = tid; i < 2048; i += 256) { d1h[i] = s1h[i]; d1l[i] = s1l[i]; }
    const uint4* s2h = (const uint4*)(w2h + (size_t)blk * 24 * 512);
    const uint4* s2l = (const uint4*)(w2l + (size_t)blk * 24 * 512);
    uint4* d2h = (uint4*)lw2h; uint4* d2l = (uint4*)lw2l;
    for (int i = tid; i < 1536; i += 256) { d2h[i] = s2h[i]; d2l[i] = s2l[i]; }
    for (int i = tid; i < 1920; i += 256) ls_cm[i] = cm[((i >> 6) * 2 + t1) * 64 + (i & 63)];
  }
  // hoisted per-thread constants
  const int cc = lane & 15;
  float bhhn = (cc < 8) ? bhh[t1 * 768 + 512 + hd1 + cc] : 0.f;
  float mrz_b = 0.f, mgi_b = 0.f, mgh_b = 0.f;
  if (cc < 8) {
    int gc = (cc < 4) ? (hd2 + cc) : (256 + hd2 + (cc - 4));
    mrz_b = mbih[gc] + mbhh[gc];
  } else if (cc < 12) {
    int gn = 512 + hd2 + (cc - 8);
    mgi_b = mbih[gn];
    mgh_b = mbhh[gn];
  }

  // gi_x prefetch registers (step 0 preloaded here; s+1 prefetched in phase-2)
  float gq[8];
  {
    const float* grow = gix + (size_t)(blk * 30 + 0) * 2048;
    #pragma unroll
    for (int i = 0; i < 4; ++i) {
      int r = w * 16 + (lane >> 4) * 4 + i;
      gq[i]     = grow[r * 32 + cc];
      gq[4 + i] = grow[r * 32 + 16 + (cc & 7)];
    }
  }
  __syncthreads();

  short8 ah1[8], al1[8];   // apk[s-1] (G1; reused by m2)
  short8 xh2[8], xl2[8];   // own-task hpk[s] (loaded phase-2 of s-1; used by G2)
  float hold0 = 0.f, hold1 = 0.f;   // own h_task values (mapping step-invariant)
  float hm_reg = 0.f;               // own h_meta value

  for (int s = 0; s < 30; ++s) {
    // ---------- phase 1: task GRUs ----------
    f32x4 a1[2], a2[2];
    #pragma unroll
    for (int i = 0; i < 2; ++i) {
      a1[i] = (f32x4){0.f, 0.f, 0.f, 0.f};
      a2[i] = (f32x4){0.f, 0.f, 0.f, 0.f};
    }
    if (s > 0) {
      uint4 ra[16];
      const u32* Ap = apk + (size_t)(arow * 30 + (s - 1)) * 256 + ko;
      #pragma unroll
      for (int k = 0; k < 8; ++k) {
        cload16(ra[2 * k],     Ap + k * 32);
        cload16(ra[2 * k + 1], Ap + k * 32 + 4);
      }
      __builtin_amdgcn_sched_barrier(0);
      // a2 overlaps the coherent-load window (xh2/xl2 already in regs)
      #pragma unroll
      for (int k = 0; k < 8; ++k) {
        #pragma unroll
        for (int nt = 0; nt < 2; ++nt) {
          short8 bh2 = *(const short8*)(lw1h + ((8 + k) * 2 + nt) * 512 + lane * 8);
          short8 bl2 = *(const short8*)(lw1l + ((8 + k) * 2 + nt) * 512 + lane * 8);
          a2[nt] = mfma16(xh2[k], bh2, a2[nt]);
          a2[nt] = mfma16(xl2[k], bh2, a2[nt]);
          a2[nt] = mfma16(xh2[k], bl2, a2[nt]);
        }
      }
      cwait();
      #pragma unroll
      for (int k = 0; k < 8; ++k) {
        unpack8(ra[2 * k], ra[2 * k + 1], ah1[k], al1[k]);
        #pragma unroll
        for (int nt = 0; nt < 2; ++nt) {
          short8 bh = *(const short8*)(lw1h + (k * 2 + nt) * 512 + lane * 8);
          short8 bl = *(const short8*)(lw1l + (k * 2 + nt) * 512 + lane * 8);
          a1[nt] = mfma16(ah1[k], bh, a1[nt]);
          a1[nt] = mfma16(al1[k], bh, a1[nt]);
          a1[nt] = mfma16(ah1[k], bl, a1[nt]);
        }
      }
    }
    // gates -> LDS (C layout: row=(l>>4)*4+i, col=l&15)
    #pragma unroll
    for (int i = 0; i < 4; ++i) {
      int rl = (lane >> 4) * 4 + i;
      ls_rz[(w * 16 + rl) * 16 + cc] = a1[0][i] + a2[0][i] + gq[i];
      if (cc < 8) {
        ls_gi[(w * 16 + rl) * 8 + cc] = a1[1][i] + gq[4 + i];
        ls_gh[(w * 16 + rl) * 8 + cc] = a2[1][i] + bhhn;
      }
    }
    __syncthreads();
    {
      int item = lane;
      int rl = item >> 3, c = item & 7;
      float rv = ls_rz[(w * 16 + rl) * 16 + c], zv = ls_rz[(w * 16 + rl) * 16 + 8 + c];
      float gi = ls_gi[(w * 16 + rl) * 8 + c], gh = ls_gh[(w * 16 + rl) * 8 + c];
      float r = 1.f / (1.f + expf(-rv));
      float z = 1.f / (1.f + expf(-zv));
      float n = tanhf(gi + r * gh);
      int b = w * 16 + rl;
      float m = ls_cm[s * 64 + b];
      float hnew = (1.f - z) * n + z * hold0;
      float hout = (m > 0.5f) ? hnew : hold0;
      hold0 = hout;
      int oo = (((s + 1) * 2 + t1) * 64 + b) * 256 + hd1 + c;
      u16 xh, xl; split_bf16(hout, xh, xl);
      astore(hpk + oo, (u32)xh | ((u32)xl << 16));
    }
    {
      int item = 64 + lane;
      int rl = item >> 3, c = item & 7;
      float rv = ls_rz[(w * 16 + rl) * 16 + c], zv = ls_rz[(w * 16 + rl) * 16 + 8 + c];
      float gi = ls_gi[(w * 16 + rl) * 8 + c], gh = ls_gh[(w * 16 + rl) * 8 + c];
      float r = 1.f / (1.f + expf(-rv));
      float z = 1.f / (1.f + expf(-zv));
      float n = tanhf(gi + r * gh);
      int b = w * 16 + rl;
      float m = ls_cm[s * 64 + b];
      float hnew = (1.f - z) * n + z * hold1;
      float hout = (m > 0.5f) ? hnew : hold1;
      hold1 = hout;
      int oo = (((s + 1) * 2 + t1) * 64 + b) * 256 + hd1 + c;
      u16 xh, xl; split_bf16(hout, xh, xl);
      astore(hpk + oo, (u32)xh | ((u32)xl << 16));
    }
    gridbar(slots, blk, epoch);

    // ---------- phase 2: meta GRU ----------
    f32x4 m1 = (f32x4){0.f, 0.f, 0.f, 0.f};
    f32x4 m2 = (f32x4){0.f, 0.f, 0.f, 0.f};
    {
      uint4 rx[16], ry[16];
      const u32* Hp = hpk + (size_t)(((s + 1) * 2 + t1) * 64 + arow) * 256 + ko;
      const u32* Hq = hpk + (size_t)(((s + 1) * 2 + (1 - t1)) * 64 + arow) * 256 + ko;
      #pragma unroll
      for (int k = 0; k < 8; ++k) {
        cload16(rx[2 * k],     Hp + k * 32);
        cload16(rx[2 * k + 1], Hp + k * 32 + 4);
      }
      #pragma unroll
      for (int k = 0; k < 8; ++k) {
        cload16(ry[2 * k],     Hq + k * 32);
        cload16(ry[2 * k + 1], Hq + k * 32 + 4);
      }
      __builtin_amdgcn_sched_barrier(0);
      // gi_x prefetch for next step (normal cached load; overlaps RTT)
      if (s < 29) {
        const float* grow = gix + (size_t)(blk * 30 + s + 1) * 2048;
        #pragma unroll
        for (int i = 0; i < 4; ++i) {
          int r = w * 16 + (lane >> 4) * 4 + i;
          gq[i]     = grow[r * 32 + cc];
          gq[4 + i] = grow[r * 32 + 16 + (cc & 7)];
        }
      }
      // m2 overlaps the load window (ah1 in regs)
      if (s > 0) {
        #pragma unroll
        for (int k = 0; k < 8; ++k) {
          short8 bh = *(const short8*)(lw2h + (16 + k) * 512 + lane * 8);
          short8 bl = *(const short8*)(lw2l + (16 + k) * 512 + lane * 8);
          m2 = mfma16(ah1[k], bh, m2);
          m2 = mfma16(al1[k], bh, m2);
          m2 = mfma16(ah1[k], bl, m2);
        }
      }
      cwait();
      #pragma unroll
      for (int k = 0; k < 8; ++k) {
        unpack8(rx[2 * k], rx[2 * k + 1], xh2[k], xl2[k]);
        short8 bh = *(const short8*)(lw2h + k * 512 + lane * 8);
        short8 bl = *(const short8*)(lw2l + k * 512 + lane * 8);
        m1 = mfma16(xh2[k], bh, m1);
        m1 = mfma16(xl2[k], bh, m1);
        m1 = mfma16(xh2[k], bl, m1);
      }
      #pragma unroll
      for (int k = 0; k < 8; ++k) {
        short8 yh, yl;
        unpack8(ry[2 * k], ry[2 * k + 1], yh, yl);
        short8 bh = *(const short8*)(lw2h + (8 + k) * 512 + lane * 8);
        short8 bl = *(const short8*)(lw2l + (8 + k) * 512 + lane * 8);
        m1 = mfma16(yh, bh, m1);
        m1 = mfma16(yl, bh, m1);
        m1 = mfma16(yh, bl, m1);
      }
    }
    #pragma unroll
    for (int i = 0; i < 4; ++i) {
      int rl = (lane >> 4) * 4 + i;
      if (cc < 8) {
        ls_rz[(w * 16 + rl) * 16 + cc] = m1[i] + m2[i] + mrz_b;
      } else if (cc < 12) {
        ls_gi[(w * 16 + rl) * 8 + (cc - 8)] = m1[i] + mgi_b;
        ls_gh[(w * 16 + rl) * 8 + (cc - 8)] = m2[i] + mgh_b;
      }
    }
    __syncthreads();
    {
      int rl = lane >> 2, c = lane & 3;
      float rv = ls_rz[(w * 16 + rl) * 16 + c], zv = ls_rz[(w * 16 + rl) * 16 + 4 + c];
      float gi = ls_gi[(w * 16 + rl) * 8 + c], gh = ls_gh[(w * 16 + rl) * 8 + c];
      float r = 1.f / (1.f + expf(-rv));
      float z = 1.f / (1.f + expf(-zv));
      float n = tanhf(gi + r * gh);
      int b = w * 16 + rl;
      int g2 = hd2 + c;
      float hmnew = (1.f - z) * n + z * hm_reg;
      hm_reg = hmnew;
      int ar = b * 30 + s;
      u16 xh, xl; split_bf16(hmnew, xh, xl);
      astore(apk + ar * 256 + g2, (u32)xh | ((u32)xl << 16));
    }
    gridbar(slots, blk, epoch);
  }
}

// ---------------- score_new GEMM: [1920,256] x [256,20000] (3-pass split bf16) ----------------
__global__ __launch_bounds__(256) void k_gnew(const u32* __restrict__ apk,
                                              const u16* __restrict__ wnh, const u16* __restrict__ wnl,
                                              const float* __restrict__ bnew,
                                              float* __restrict__ out) {
  int bid = blockIdx.x;
  int mb = bid / 157, nb = bid % 157;
  int tid = threadIdx.x, lane = tid & 63, w = tid >> 6;
  int ko = (lane >> 4) * 8;
  f32x4 acc[2][8];
  #pragma unroll
  for (int mi = 0; mi < 2; ++mi)
    #pragma unroll
    for (int nt = 0; nt < 8; ++nt) acc[mi][nt] = (f32x4){0.f, 0.f, 0.f, 0.f};
  #pragma unroll
  for (int ks = 0; ks < 8; ++ks) {
    short8 ah[2], al[2];
    #pragma unroll
    for (int mi = 0; mi < 2; ++mi) {
      int r = mb * 128 + (w * 2 + mi) * 16 + (lane & 15);
      vload8(apk + (size_t)r * 256 + ks * 32 + ko, ah[mi], al[mi]);
    }
    #pragma unroll
    for (int nt = 0; nt < 8; ++nt) {
      int un = (nb * 8 + nt) * 8 + ks;
      short8 bh = *(const short8*)(wnh + (size_t)un * 512 + lane * 8);
      short8 bl = *(const short8*)(wnl + (size_t)un * 512 + lane * 8);
      #pragma unroll
      for (int mi = 0; mi < 2; ++mi) {
        acc[mi][nt] = mfma16(ah[mi], bh, acc[mi][nt]);
        acc[mi][nt] = mfma16(al[mi], bh, acc[mi][nt]);
        acc[mi][nt] = mfma16(ah[mi], bl, acc[mi][nt]);
      }
    }
  }
  #pragma unroll
  for (int mi = 0; mi < 2; ++mi)
    #pragma unroll
    for (int nt = 0; nt < 8; ++nt) {
      int col = nb * 128 + nt * 16 + (lane & 15);
      if (col < 20000) {
        float bn = bnew[col];
        #pragma unroll
        for (int i = 0; i < 4; ++i) {
          int r = mb * 128 + (w * 2 + mi) * 16 + (lane >> 4) * 4 + i;
          out[(size_t)r * 20000 + col] = acc[mi][nt][i] + bn;
        }
      }
    }
}

// ---------------- copy scores: sparse scatter only (zero-fill done by k_rnn helpers) ----------------
__global__ __launch_bounds__(256) void k_copy(const u32* __restrict__ hpk,
                                              const int* __restrict__ cv,
                                              const float* __restrict__ wc,
                                              const float* __restrict__ bc,
                                              float* __restrict__ out) {
  int u = blockIdx.x;                 // t*1920 + b*30 + s
  int t = u / 1920;
  int rem = u % 1920;
  int b = rem / 30, s = rem % 30;
  int tid = threadIdx.x, lane = tid & 63, w = tid >> 6;
  float* orow = out + (size_t)(1 + t) * 38400000 + (size_t)(b * 30 + s) * 20000;
  const u32* hp = hpk + (size_t)(((s + 1) * 2 + t) * 64 + b) * 256;
  uint4 hq = *(const uint4*)(hp + lane * 4);
  float4 h4;
  h4.x = unpack_hl(hq.x); h4.y = unpack_hl(hq.y);
  h4.z = unpack_hl(hq.z); h4.w = unpack_hl(hq.w);
  int base = u * 20;
  for (int c = w; c < 20; c += 4) {
    int idx = cv[base + c];
    const float* wr = wc + ((size_t)t * 20000 + idx) * 256;
    float4 w4 = *(const float4*)(wr + lane * 4);
    float d = h4.x * w4.x + h4.y * w4.y + h4.z * w4.z + h4.w * w4.w;
    #pragma unroll
    for (int m = 32; m >= 1; m >>= 1) d += __shfl_xor(d, m, 64);
    if (lane == 0) orow[idx] = d + bc[t * 20000 + idx];
  }
}

extern "C" void kernel_launch(void* const* d_in, const int* in_sizes, int n_in,
                              void* d_out, int out_size, void* d_ws, size_t ws_size,
                              hipStream_t stream) {
  const int* iv = (const int*)d_in[1];
  const int* cv = (const int*)d_in[2];
  const float* emb = (const float*)d_in[3];
  const float* Wih = (const float*)d_in[4];
  const float* Whh = (const float*)d_in[5];
  const float* bih = (const float*)d_in[6];
  const float* bhh = (const float*)d_in[7];
  const float* mWih = (const float*)d_in[8];
  const float* mWhh = (const float*)d_in[9];
  const float* mbih = (const float*)d_in[10];
  const float* mbhh = (const float*)d_in[11];
  const float* Wnew = (const float*)d_in[12];
  const float* bnew = (const float*)d_in[13];
  const float* Wcopy = (const float*)d_in[14];
  const float* bcopy = (const float*)d_in[15];
  float* out = (float*)d_out;
  char* ws = (char*)d_ws;

  size_t o = 0;
  auto take = [&](size_t sz) { size_t r = o; o += sz; return r; };
  size_t BAR = take(256);        // 64 contiguous u32 flags
  size_t CM  = take(15360);
  size_t EBH = take(983040);
  size_t EBL = take(983040);
  size_t HPK = take(4063232);    // packed bf16 hi|lo task-h [31][2][64][256] u32
  size_t APK = take(1966080);    // packed bf16 hi|lo meta-h [1920][256] u32
  size_t GIX = take(15728640);   // fp32 gi_x [64 blk][30][64][32]
  size_t W1H = take(2621440);
  size_t W1L = take(2621440);
  size_t W2H = take(1572864);
  size_t W2L = take(1572864);
  size_t WNH = take(10289152);
  size_t WNL = take(10289152);
  if (ws_size < o) return;   // insufficient workspace: fail loudly via absmax

  hipFuncSetAttribute(reinterpret_cast<const void*>(k_rnn),
                      hipFuncAttributeMaxDynamicSharedMemorySize, RNN_LDS);

  hipMemsetAsync(ws + BAR, 0, 256, stream);
  hipMemsetAsync(ws + HPK, 0, 131072, stream);

  k_pool<<<3840, 128, 0, stream>>>(iv, emb, (u16*)(ws + EBH), (u16*)(ws + EBL), (float*)(ws + CM));
  k_swz<<<3536, 256, 0, stream>>>(Wih, Whh, mWih, mWhh, Wnew,
                                  (u16*)(ws + W1H), (u16*)(ws + W1L),
                                  (u16*)(ws + W2H), (u16*)(ws + W2L),
                                  (u16*)(ws + WNH), (u16*)(ws + WNL));
  k_gix<<<64, 256, 0, stream>>>((const u16*)(ws + EBH), (const u16*)(ws + EBL),
                                (const u16*)(ws + W1H), (const u16*)(ws + W1L),
                                bih, bhh, (float*)(ws + GIX));
  k_rnn<<<NB_ + HELPERS_, 256, RNN_LDS, stream>>>(
      (const u16*)(ws + W1H), (const u16*)(ws + W1L),
      (const u16*)(ws + W2H), (const u16*)(ws + W2L),
      (const float*)(ws + GIX), bhh, mbih, mbhh,
      (const float*)(ws + CM),
      (u32*)(ws + HPK), (u32*)(ws + APK),
      (u32*)(ws + BAR),
      out + 38400000);
  k_gnew<<<2355, 256, 0, stream>>>((const u32*)(ws + APK),
                                   (const u16*)(ws + WNH), (const u16*)(ws + WNL),
                                   bnew, out);
  k_copy<<<3840, 256, 0, stream>>>((const u32*)(ws + HPK), cv, Wcopy, bcopy, out);
}

// Round 9
// 574.053 us; speedup vs baseline: 1.4153x; 1.1779x over previous
//
#include <hip/hip_runtime.h>

typedef unsigned short u16;
typedef unsigned int u32;
typedef unsigned long long u64;
typedef __attribute__((ext_vector_type(8))) short short8;
typedef __attribute__((ext_vector_type(4))) float f32x4;

#define NB_ 64
#define HELPERS_ 1152

static __device__ __forceinline__ f32x4 mfma16(short8 a, short8 b, f32x4 c) {
  return __builtin_amdgcn_mfma_f32_16x16x32_bf16(a, b, c, 0, 0, 0);
}

// split fp32 -> bf16 hi + bf16 lo  (x ~= hi + lo, residual ~2^-17 * |x|)
static __device__ __forceinline__ void split_bf16(float x, u16& hi, u16& lo) {
  unsigned u = __float_as_uint(x);
  unsigned r = (u + 0x7fffu + ((u >> 16) & 1u)) >> 16;
  hi = (u16)r;
  float fh = __uint_as_float(r << 16);
  float xl = x - fh;
  unsigned ul = __float_as_uint(xl);
  unsigned rl2 = (ul + 0x7fffu + ((ul >> 16) & 1u)) >> 16;
  lo = (u16)rl2;
}

// write-through publication store to the coherence point (proven r1-r7)
static __device__ __forceinline__ void astore(u32* p, u32 v) {
  __hip_atomic_store(p, v, __ATOMIC_RELAXED, __HIP_MEMORY_SCOPE_AGENT);
}
static __device__ __forceinline__ void unpack8(const uint4& a, const uint4& b,
                                               short8& h, short8& l) {
  u32 wb[8] = {a.x, a.y, a.z, a.w, b.x, b.y, b.z, b.w};
  #pragma unroll
  for (int j = 0; j < 8; ++j) {
    h[j] = (short)(wb[j] & 0xffffu);
    l[j] = (short)(wb[j] >> 16);
  }
}
static __device__ __forceinline__ float unpack_hl(u32 pk) {
  return __uint_as_float((pk & 0xffffu) << 16) + __uint_as_float(pk & 0xffff0000u);
}
static __device__ __forceinline__ void vload8(const u32* p, short8& h, short8& l) {
  uint4 a = *(const uint4*)p;
  uint4 b = *(const uint4*)(p + 4);
  unpack8(a, b, h, l);
}

// ---------------- pooling: emb gather + mean over valid items ----------------
__global__ __launch_bounds__(128) void k_pool(const int* __restrict__ iv,
                                              const float* __restrict__ emb,
                                              u16* __restrict__ ebh, u16* __restrict__ ebl,
                                              float* __restrict__ cm) {
  int u = blockIdx.x;             // u = (s*2+t)*64+b
  int s = u >> 7;
  int t = (u >> 6) & 1;
  int b = u & 63;
  int d = threadIdx.x;
  const int ibase = ((t * 64 + b) * 30 + s) * 12;
  float sum = 0.f;
  int cnt = 0;
  for (int k = 0; k < 12; ++k) {
    int idx = iv[ibase + k];
    if (idx > 0) { cnt++; sum += emb[(size_t)idx * 128 + d]; }
  }
  float den = (cnt > 0) ? (float)cnt : 1.f;
  float v = sum / den;
  u16 hi, lo; split_bf16(v, hi, lo);
  ebh[(size_t)u * 128 + d] = hi;
  ebl[(size_t)u * 128 + d] = lo;
  if (d == 0) cm[u] = (cnt > 0) ? 1.f : 0.f;
}

// ---------------- weight swizzle into MFMA B-fragment layout ----------------
// B-frag (16x16x32): lane l holds B[k=(l>>4)*8+j][n=l&15], j=0..7
// w1: 64 blk * 20 ks * 2 nt; ks 0..7 WihH(K=256), 8..15 Whh(K=256), 16..19 WihX(K=128)
// w2: 64 blk * 24 ks; ks 0..7 mWih OWN task (t1=blk>>5), 8..15 mWih other task, 16..23 mWhh
__global__ __launch_bounds__(256) void k_swz(const float* __restrict__ Wih,
                                             const float* __restrict__ Whh,
                                             const float* __restrict__ mWih,
                                             const float* __restrict__ mWhh,
                                             const float* __restrict__ Wnew,
                                             u16* __restrict__ w1h, u16* __restrict__ w1l,
                                             u16* __restrict__ w2h, u16* __restrict__ w2l,
                                             u16* __restrict__ wnh, u16* __restrict__ wnl) {
  int gu = blockIdx.x * 4 + (threadIdx.x >> 6);
  int lane = threadIdx.x & 63;
  int ko = (lane >> 4) * 8;
  int cl = lane & 15;
  float src[8];
  if (gu < 2560) {
    int blk = gu / 40, r = gu % 40, ksIdx = r >> 1, nt = r & 1;
    int t = blk >> 5, hd0 = (blk & 31) * 8;
    int c = nt * 16 + cl;
    if (c < 24) {
      int gc = (c < 8) ? (hd0 + c) : (c < 16) ? (256 + hd0 + (c - 8)) : (512 + hd0 + (c - 16));
      const float* wrow; int kk;
      if (ksIdx < 8)       { wrow = Wih + (size_t)(t * 768 + gc) * 384 + 128; kk = ksIdx * 32 + ko; }
      else if (ksIdx < 16) { wrow = Whh + (size_t)(t * 768 + gc) * 256;       kk = (ksIdx - 8) * 32 + ko; }
      else                 { wrow = Wih + (size_t)(t * 768 + gc) * 384;       kk = (ksIdx - 16) * 32 + ko; }
      #pragma unroll
      for (int j = 0; j < 8; ++j) src[j] = wrow[kk + j];
    } else {
      #pragma unroll
      for (int j = 0; j < 8; ++j) src[j] = 0.f;
    }
    int off = gu * 512 + lane * 8;
    #pragma unroll
    for (int j = 0; j < 8; ++j) { u16 h, l; split_bf16(src[j], h, l); w1h[off + j] = h; w1l[off + j] = l; }
  } else if (gu < 4096) {
    int g2 = gu - 2560;
    int blk = g2 / 24, ksIdx = g2 % 24;
    int t1 = blk >> 5;
    int hd0 = blk * 4;
    int c = cl;
    if (c < 12) {
      int gc = (c < 4) ? (hd0 + c) : (c < 8) ? (256 + hd0 + (c - 4)) : (512 + hd0 + (c - 8));
      if (ksIdx < 16) {
        int chunk = (ksIdx < 8) ? (t1 * 8 + ksIdx) : ((1 - t1) * 8 + (ksIdx - 8));
        int kk = chunk * 32 + ko;
        #pragma unroll
        for (int j = 0; j < 8; ++j) src[j] = mWih[(size_t)gc * 512 + kk + j];
      } else {
        int kk = (ksIdx - 16) * 32 + ko;
        #pragma unroll
        for (int j = 0; j < 8; ++j) src[j] = mWhh[(size_t)gc * 256 + kk + j];
      }
    } else {
      #pragma unroll
      for (int j = 0; j < 8; ++j) src[j] = 0.f;
    }
    int off = g2 * 512 + lane * 8;
    #pragma unroll
    for (int j = 0; j < 8; ++j) { u16 h, l; split_bf16(src[j], h, l); w2h[off + j] = h; w2l[off + j] = l; }
  } else if (gu < 14144) {
    int g3 = gu - 4096;
    int gnt = g3 >> 3, ks = g3 & 7;
    int col = gnt * 16 + cl;
    if (col < 20000) {
      int kk = ks * 32 + ko;
      #pragma unroll
      for (int j = 0; j < 8; ++j) src[j] = Wnew[(size_t)col * 256 + kk + j];
    } else {
      #pragma unroll
      for (int j = 0; j < 8; ++j) src[j] = 0.f;
    }
    int off = g3 * 512 + lane * 8;
    #pragma unroll
    for (int j = 0; j < 8; ++j) { u16 h, l; split_bf16(src[j], h, l); wnh[off + j] = h; wnl[off + j] = l; }
  }
}

// ---------------- gi_x precompute: gi_x = x @ WihX^T (+bias folds) ----------------
// layout: gix[blk][s][row 0..63][32]: cols 0..15 = r,z (+bih+bhh), 16..23 = n (+bih)
__global__ __launch_bounds__(256) void k_gix(const u16* __restrict__ ebh, const u16* __restrict__ ebl,
                                             const u16* __restrict__ w1h, const u16* __restrict__ w1l,
                                             const float* __restrict__ bih, const float* __restrict__ bhh,
                                             float* __restrict__ gix) {
  int blk = blockIdx.x;
  int t1 = blk >> 5, hd1 = (blk & 31) * 8;
  int tid = threadIdx.x, lane = tid & 63, w = tid >> 6;
  int arow = w * 16 + (lane & 15);
  int ko = (lane >> 4) * 8;
  __shared__ u16 lwh[4096], lwl[4096];
  {
    const uint4* sh = (const uint4*)(w1h + ((size_t)blk * 40 + 32) * 512);
    const uint4* sl = (const uint4*)(w1l + ((size_t)blk * 40 + 32) * 512);
    uint4* dh = (uint4*)lwh; uint4* dl = (uint4*)lwl;
    for (int i = tid; i < 512; i += 256) { dh[i] = sh[i]; dl[i] = sl[i]; }
  }
  int c = lane & 15;
  float brz, bn = 0.f;
  {
    int gc = (c < 8) ? (hd1 + c) : (256 + hd1 + (c - 8));
    brz = bih[t1 * 768 + gc] + bhh[t1 * 768 + gc];
    if (c < 8) bn = bih[t1 * 768 + 512 + hd1 + c];
  }
  __syncthreads();
  for (int s = 0; s < 30; ++s) {
    f32x4 a3[2];
    a3[0] = (f32x4){0.f, 0.f, 0.f, 0.f};
    a3[1] = (f32x4){0.f, 0.f, 0.f, 0.f};
    const u16* Xh = ebh + (size_t)((s * 2 + t1) * 64 + arow) * 128;
    const u16* Xl = ebl + (size_t)((s * 2 + t1) * 64 + arow) * 128;
    #pragma unroll
    for (int k = 0; k < 4; ++k) {
      short8 xh = *(const short8*)(Xh + k * 32 + ko);
      short8 xl = *(const short8*)(Xl + k * 32 + ko);
      #pragma unroll
      for (int nt = 0; nt < 2; ++nt) {
        short8 bh = *(const short8*)(lwh + (k * 2 + nt) * 512 + lane * 8);
        short8 bl = *(const short8*)(lwl + (k * 2 + nt) * 512 + lane * 8);
        a3[nt] = mfma16(xh, bh, a3[nt]);
        a3[nt] = mfma16(xl, bh, a3[nt]);
        a3[nt] = mfma16(xh, bl, a3[nt]);
      }
    }
    float* grow = gix + (size_t)(blk * 30 + s) * 64 * 32;
    #pragma unroll
    for (int i = 0; i < 4; ++i) {
      int r = w * 16 + (lane >> 4) * 4 + i;
      grow[r * 32 + c] = a3[0][i] + brz;
      if (c < 8) grow[r * 32 + 16 + c] = a3[1][i] + bn;
    }
  }
}

// ---------------- persistent GRU recurrence ----------------
// Split barrier: arrive = syncthreads (drains all waves' stores) + flag store;
// wait = every wave's 64 lanes poll the 64 flags via coherent loads, waves
// release independently (no trailing block sync). Local-only compute (retained
// regs + LDS weights) sits between arrive and wait to hide the straggler window.
static __device__ __forceinline__ void bar_arrive(u32* slots, int blk, int epoch) {
  __syncthreads();              // all waves' publication stores drained
  if (threadIdx.x == 0) astore(slots + blk, (u32)epoch);
}
static __device__ __forceinline__ void bar_wait(u32* slots, int epoch) {
  int lane = threadIdx.x & 63;
  u32 v;
  for (;;) {
    asm volatile("global_load_dword %0, %1, off sc0 sc1\n\ts_waitcnt vmcnt(0)"
                 : "=v"(v) : "v"(slots + lane) : "memory");
    if ((int)v >= epoch) break;
  }
}

// dynamic LDS layout (bytes):
//   [0)       w1h  32 units * 1024 = 32768
//   [32768)   w1l  32768
//   [65536)   w2h  24 units * 1024 = 24576
//   [90112)   w2l  24576            -> 114688
//   [114688)  ls_rz float[4][16][16] 4096
//   [118784)  ls_gi float[4][16][8]  2048
//   [120832)  ls_gh float[4][16][8]  2048
//   [122880)  ls_cm float[30][64]    7680  -> total 130560
#define RNN_LDS 130560

__global__ __launch_bounds__(256, 1) void k_rnn(
    const u16* __restrict__ w1h, const u16* __restrict__ w1l,
    const u16* __restrict__ w2h, const u16* __restrict__ w2l,
    const float* __restrict__ gix,
    const float* __restrict__ bhh,
    const float* __restrict__ mbih, const float* __restrict__ mbhh,
    const float* __restrict__ cm,
    u32* __restrict__ hpk,       // packed (hi|lo<<16) task-h   [31][2][64][256]
    u32* __restrict__ apk,       // packed (hi|lo<<16) meta-h   [1920][256] (b*30+s)
    u32* slots,
    float* __restrict__ zout) {  // sparse-score region to zero (helpers)
  // ---- helper blocks: zero the 307.2 MB copy-score region (nt stores), exit ----
  if (blockIdx.x >= NB_) {
    const size_t totalf4 = 19200000;   // 307,200,000 B / 16
    size_t idx = (size_t)(blockIdx.x - NB_) * 256 + threadIdx.x;
    size_t stride = (size_t)HELPERS_ * 256;
    f32x4 z4 = {0.f, 0.f, 0.f, 0.f};
    f32x4* zp = (f32x4*)zout;
    for (size_t i = idx; i < totalf4; i += stride)
      __builtin_nontemporal_store(z4, zp + i);
    return;
  }

  extern __shared__ char smem[];
  u16* lw1h = (u16*)smem;
  u16* lw1l = (u16*)(smem + 32768);
  u16* lw2h = (u16*)(smem + 65536);
  u16* lw2l = (u16*)(smem + 90112);
  float* ls_rz = (float*)(smem + 114688);
  float* ls_gi = (float*)(smem + 118784);
  float* ls_gh = (float*)(smem + 120832);
  float* ls_cm = (float*)(smem + 122880);

  const int blk = blockIdx.x;
  const int tid = threadIdx.x;
  const int lane = tid & 63;
  const int w = tid >> 6;
  const int t1 = blk >> 5;
  const int hd1 = (blk & 31) * 8;
  const int hd2 = blk * 4;
  const int arow = w * 16 + (lane & 15);
  const int ko = (lane >> 4) * 8;
  int epoch = 0;

  // one-time: weights -> LDS, cm -> LDS
  {
    const uint4* s1h = (const uint4*)(w1h + (size_t)blk * 40 * 512);
    const uint4* s1l = (const uint4*)(w1l + (size_t)blk * 40 * 512);
    uint4* d1h = (uint4*)lw1h; uint4* d1l = (uint4*)lw1l;
    for (int i = tid; i < 2048; i += 256) { d1h[i] = s1h[i]; d1l[i] = s1l[i]; }
    const uint4* s2h = (const uint4*)(w2h + (size_t)blk * 24 * 512);
    const uint4* s2l = (const uint4*)(w2l + (size_t)blk * 24 * 512);
    uint4* d2h = (uint4*)lw2h; uint4* d2l = (uint4*)lw2l;
    for (int i = tid; i < 1536; i += 256) { d2h[i] = s2h[i]; d2l[i] = s2l[i]; }
    for (int i = tid; i < 1920; i += 256) ls_cm[i] = cm[((i >> 6) * 2 + t1) * 64 + (i & 63)];
  }
  // hoisted per-thread constants
  const int cc = lane & 15;
  float bhhn = (cc < 8) ? bhh[t1 * 768 + 512 + hd1 + cc] : 0.f;
  float mrz_b = 0.f, mgi_b = 0.f, mgh_b = 0.f;
  if (cc < 8) {
    int gc = (cc < 4) ? (hd2 + cc) : (256 + hd2 + (cc - 4));
    mrz_b = mbih[gc] + mbhh[gc];
  } else if (cc < 12) {
    int gn = 512 + hd2 + (cc - 8);
    mgi_b = mbih[gn];
    mgh_b = mbhh[gn];
  }

  // gi_x prefetch registers (step 0 preloaded here; s+1 prefetched pre-poll in phase-2)
  float gq[8];
  {
    const float* grow = gix + (size_t)(blk * 30 + 0) * 2048;
    #pragma unroll
    for (int i = 0; i < 4; ++i) {
      int r = w * 16 + (lane >> 4) * 4 + i;
      gq[i]     = grow[r * 32 + cc];
      gq[4 + i] = grow[r * 32 + 16 + (cc & 7)];
    }
  }
  __syncthreads();

  short8 ah1[8], al1[8];   // apk[s-1] (G1; reused by m2)
  short8 xh2[8], xl2[8];   // own-task hpk[s] (loaded phase-2 of s-1; used by a2s)
  f32x4 a2s[2];            // Whh @ h_task, precomputed at end of previous iteration
  a2s[0] = (f32x4){0.f, 0.f, 0.f, 0.f};
  a2s[1] = (f32x4){0.f, 0.f, 0.f, 0.f};
  float hold0 = 0.f, hold1 = 0.f;   // own h_task values (mapping step-invariant)
  float hm_reg = 0.f;               // own h_meta value

  for (int s = 0; s < 30; ++s) {
    // ---------- phase 1: task GRUs ----------
    f32x4 a1[2];
    a1[0] = (f32x4){0.f, 0.f, 0.f, 0.f};
    a1[1] = (f32x4){0.f, 0.f, 0.f, 0.f};
    if (s > 0) {
      bar_wait(slots, epoch);
      // normal cached loads: apk[s-1] lines are first-touched AFTER the barrier
      const u32* Ap = apk + (size_t)(arow * 30 + (s - 1)) * 256 + ko;
      uint4 ra[16];
      #pragma unroll
      for (int k = 0; k < 8; ++k) {
        ra[2 * k]     = *(const uint4*)(Ap + k * 32);
        ra[2 * k + 1] = *(const uint4*)(Ap + k * 32 + 4);
      }
      #pragma unroll
      for (int k = 0; k < 8; ++k) {
        unpack8(ra[2 * k], ra[2 * k + 1], ah1[k], al1[k]);
        #pragma unroll
        for (int nt = 0; nt < 2; ++nt) {
          short8 bh = *(const short8*)(lw1h + (k * 2 + nt) * 512 + lane * 8);
          short8 bl = *(const short8*)(lw1l + (k * 2 + nt) * 512 + lane * 8);
          a1[nt] = mfma16(ah1[k], bh, a1[nt]);
          a1[nt] = mfma16(al1[k], bh, a1[nt]);
          a1[nt] = mfma16(ah1[k], bl, a1[nt]);
        }
      }
    }
    // gates -> LDS (per-wave slices; intra-wave ordering via lgkmcnt)
    #pragma unroll
    for (int i = 0; i < 4; ++i) {
      int rl = (lane >> 4) * 4 + i;
      ls_rz[(w * 16 + rl) * 16 + cc] = a1[0][i] + a2s[0][i] + gq[i];
      if (cc < 8) {
        ls_gi[(w * 16 + rl) * 8 + cc] = a1[1][i] + gq[4 + i];
        ls_gh[(w * 16 + rl) * 8 + cc] = a2s[1][i] + bhhn;
      }
    }
    asm volatile("s_waitcnt lgkmcnt(0)" ::: "memory");
    {
      int item = lane;
      int rl = item >> 3, c = item & 7;
      float rv = ls_rz[(w * 16 + rl) * 16 + c], zv = ls_rz[(w * 16 + rl) * 16 + 8 + c];
      float gi = ls_gi[(w * 16 + rl) * 8 + c], gh = ls_gh[(w * 16 + rl) * 8 + c];
      float r = 1.f / (1.f + expf(-rv));
      float z = 1.f / (1.f + expf(-zv));
      float n = tanhf(gi + r * gh);
      int b = w * 16 + rl;
      float m = ls_cm[s * 64 + b];
      float hnew = (1.f - z) * n + z * hold0;
      float hout = (m > 0.5f) ? hnew : hold0;
      hold0 = hout;
      int oo = (((s + 1) * 2 + t1) * 64 + b) * 256 + hd1 + c;
      u16 xh, xl; split_bf16(hout, xh, xl);
      astore(hpk + oo, (u32)xh | ((u32)xl << 16));
    }
    {
      int item = 64 + lane;
      int rl = item >> 3, c = item & 7;
      float rv = ls_rz[(w * 16 + rl) * 16 + c], zv = ls_rz[(w * 16 + rl) * 16 + 8 + c];
      float gi = ls_gi[(w * 16 + rl) * 8 + c], gh = ls_gh[(w * 16 + rl) * 8 + c];
      float r = 1.f / (1.f + expf(-rv));
      float z = 1.f / (1.f + expf(-zv));
      float n = tanhf(gi + r * gh);
      int b = w * 16 + rl;
      float m = ls_cm[s * 64 + b];
      float hnew = (1.f - z) * n + z * hold1;
      float hout = (m > 0.5f) ? hnew : hold1;
      hold1 = hout;
      int oo = (((s + 1) * 2 + t1) * 64 + b) * 256 + hd1 + c;
      u16 xh, xl; split_bf16(hout, xh, xl);
      astore(hpk + oo, (u32)xh | ((u32)xl << 16));
    }
    ++epoch;
    bar_arrive(slots, blk, epoch);

    // ---- pre-poll local work: m2 (mWhh @ h_meta, regs) + gix prefetch ----
    f32x4 m1 = (f32x4){0.f, 0.f, 0.f, 0.f};
    f32x4 m2 = (f32x4){0.f, 0.f, 0.f, 0.f};
    if (s > 0) {
      #pragma unroll
      for (int k = 0; k < 8; ++k) {
        short8 bh = *(const short8*)(lw2h + (16 + k) * 512 + lane * 8);
        short8 bl = *(const short8*)(lw2l + (16 + k) * 512 + lane * 8);
        m2 = mfma16(ah1[k], bh, m2);
        m2 = mfma16(al1[k], bh, m2);
        m2 = mfma16(ah1[k], bl, m2);
      }
    }
    if (s < 29) {
      const float* grow = gix + (size_t)(blk * 30 + s + 1) * 2048;
      #pragma unroll
      for (int i = 0; i < 4; ++i) {
        int r = w * 16 + (lane >> 4) * 4 + i;
        gq[i]     = grow[r * 32 + cc];
        gq[4 + i] = grow[r * 32 + 16 + (cc & 7)];
      }
    }
    bar_wait(slots, epoch);

    // ---------- phase 2: meta GRU ----------
    {
      // normal cached loads: hpk[s+1] lines first-touched after the barrier
      const u32* Hp = hpk + (size_t)(((s + 1) * 2 + t1) * 64 + arow) * 256 + ko;
      const u32* Hq = hpk + (size_t)(((s + 1) * 2 + (1 - t1)) * 64 + arow) * 256 + ko;
      uint4 rx[16], ry[16];
      #pragma unroll
      for (int k = 0; k < 8; ++k) {
        rx[2 * k]     = *(const uint4*)(Hp + k * 32);
        rx[2 * k + 1] = *(const uint4*)(Hp + k * 32 + 4);
        ry[2 * k]     = *(const uint4*)(Hq + k * 32);
        ry[2 * k + 1] = *(const uint4*)(Hq + k * 32 + 4);
      }
      #pragma unroll
      for (int k = 0; k < 8; ++k) {
        unpack8(rx[2 * k], rx[2 * k + 1], xh2[k], xl2[k]);
        short8 bh = *(const short8*)(lw2h + k * 512 + lane * 8);
        short8 bl = *(const short8*)(lw2l + k * 512 + lane * 8);
        m1 = mfma16(xh2[k], bh, m1);
        m1 = mfma16(xl2[k], bh, m1);
        m1 = mfma16(xh2[k], bl, m1);
      }
      #pragma unroll
      for (int k = 0; k < 8; ++k) {
        short8 yh, yl;
        unpack8(ry[2 * k], ry[2 * k + 1], yh, yl);
        short8 bh = *(const short8*)(lw2h + (8 + k) * 512 + lane * 8);
        short8 bl = *(const short8*)(lw2l + (8 + k) * 512 + lane * 8);
        m1 = mfma16(yh, bh, m1);
        m1 = mfma16(yl, bh, m1);
        m1 = mfma16(yh, bl, m1);
      }
    }
    #pragma unroll
    for (int i = 0; i < 4; ++i) {
      int rl = (lane >> 4) * 4 + i;
      if (cc < 8) {
        ls_rz[(w * 16 + rl) * 16 + cc] = m1[i] + m2[i] + mrz_b;
      } else if (cc < 12) {
        ls_gi[(w * 16 + rl) * 8 + (cc - 8)] = m1[i] + mgi_b;
        ls_gh[(w * 16 + rl) * 8 + (cc - 8)] = m2[i] + mgh_b;
      }
    }
    asm volatile("s_waitcnt lgkmcnt(0)" ::: "memory");
    {
      int rl = lane >> 2, c = lane & 3;
      float rv = ls_rz[(w * 16 + rl) * 16 + c], zv = ls_rz[(w * 16 + rl) * 16 + 4 + c];
      float gi = ls_gi[(w * 16 + rl) * 8 + c], gh = ls_gh[(w * 16 + rl) * 8 + c];
      float r = 1.f / (1.f + expf(-rv));
      float z = 1.f / (1.f + expf(-zv));
      float n = tanhf(gi + r * gh);
      int b = w * 16 + rl;
      int g2 = hd2 + c;
      float hmnew = (1.f - z) * n + z * hm_reg;
      hm_reg = hmnew;
      int ar = b * 30 + s;
      u16 xh, xl; split_bf16(hmnew, xh, xl);
      astore(apk + ar * 256 + g2, (u32)xh | ((u32)xl << 16));
    }
    ++epoch;
    bar_arrive(slots, blk, epoch);

    // ---- pre-poll local work for next step: a2s = Whh @ h_task (regs) ----
    a2s[0] = (f32x4){0.f, 0.f, 0.f, 0.f};
    a2s[1] = (f32x4){0.f, 0.f, 0.f, 0.f};
    if (s < 29) {
      #pragma unroll
      for (int k = 0; k < 8; ++k) {
        #pragma unroll
        for (int nt = 0; nt < 2; ++nt) {
          short8 bh = *(const short8*)(lw1h + ((8 + k) * 2 + nt) * 512 + lane * 8);
          short8 bl = *(const short8*)(lw1l + ((8 + k) * 2 + nt) * 512 + lane * 8);
          a2s[nt] = mfma16(xh2[k], bh, a2s[nt]);
          a2s[nt] = mfma16(xl2[k], bh, a2s[nt]);
          a2s[nt] = mfma16(xh2[k], bl, a2s[nt]);
        }
      }
    }
  }
}

// ---------------- score_new GEMM: [1920,256] x [256,20000] (3-pass split bf16) ----------------
__global__ __launch_bounds__(256) void k_gnew(const u32* __restrict__ apk,
                                              const u16* __restrict__ wnh, const u16* __restrict__ wnl,
                                              const float* __restrict__ bnew,
                                              float* __restrict__ out) {
  int bid = blockIdx.x;
  int mb = bid / 157, nb = bid % 157;
  int tid = threadIdx.x, lane = tid & 63, w = tid >> 6;
  int ko = (lane >> 4) * 8;
  f32x4 acc[2][8];
  #pragma unroll
  for (int mi = 0; mi < 2; ++mi)
    #pragma unroll
    for (int nt = 0; nt < 8; ++nt) acc[mi][nt] = (f32x4){0.f, 0.f, 0.f, 0.f};
  #pragma unroll
  for (int ks = 0; ks < 8; ++ks) {
    short8 ah[2], al[2];
    #pragma unroll
    for (int mi = 0; mi < 2; ++mi) {
      int r = mb * 128 + (w * 2 + mi) * 16 + (lane & 15);
      vload8(apk + (size_t)r * 256 + ks * 32 + ko, ah[mi], al[mi]);
    }
    #pragma unroll
    for (int nt = 0; nt < 8; ++nt) {
      int un = (nb * 8 + nt) * 8 + ks;
      short8 bh = *(const short8*)(wnh + (size_t)un * 512 + lane * 8);
      short8 bl = *(const short8*)(wnl + (size_t)un * 512 + lane * 8);
      #pragma unroll
      for (int mi = 0; mi < 2; ++mi) {
        acc[mi][nt] = mfma16(ah[mi], bh, acc[mi][nt]);
        acc[mi][nt] = mfma16(al[mi], bh, acc[mi][nt]);
        acc[mi][nt] = mfma16(ah[mi], bl, acc[mi][nt]);
      }
    }
  }
  #pragma unroll
  for (int mi = 0; mi < 2; ++mi)
    #pragma unroll
    for (int nt = 0; nt < 8; ++nt) {
      int col = nb * 128 + nt * 16 + (lane & 15);
      if (col < 20000) {
        float bn = bnew[col];
        #pragma unroll
        for (int i = 0; i < 4; ++i) {
          int r = mb * 128 + (w * 2 + mi) * 16 + (lane >> 4) * 4 + i;
          out[(size_t)r * 20000 + col] = acc[mi][nt][i] + bn;
        }
      }
    }
}

// ---------------- copy scores: sparse scatter only (zero-fill done by k_rnn helpers) ----------------
__global__ __launch_bounds__(256) void k_copy(const u32* __restrict__ hpk,
                                              const int* __restrict__ cv,
                                              const float* __restrict__ wc,
                                              const float* __restrict__ bc,
                                              float* __restrict__ out) {
  int u = blockIdx.x;                 // t*1920 + b*30 + s
  int t = u / 1920;
  int rem = u % 1920;
  int b = rem / 30, s = rem % 30;
  int tid = threadIdx.x, lane = tid & 63, w = tid >> 6;
  float* orow = out + (size_t)(1 + t) * 38400000 + (size_t)(b * 30 + s) * 20000;
  const u32* hp = hpk + (size_t)(((s + 1) * 2 + t) * 64 + b) * 256;
  uint4 hq = *(const uint4*)(hp + lane * 4);
  float4 h4;
  h4.x = unpack_hl(hq.x); h4.y = unpack_hl(hq.y);
  h4.z = unpack_hl(hq.z); h4.w = unpack_hl(hq.w);
  int base = u * 20;
  for (int c = w; c < 20; c += 4) {
    int idx = cv[base + c];
    const float* wr = wc + ((size_t)t * 20000 + idx) * 256;
    float4 w4 = *(const float4*)(wr + lane * 4);
    float d = h4.x * w4.x + h4.y * w4.y + h4.z * w4.z + h4.w * w4.w;
    #pragma unroll
    for (int m = 32; m >= 1; m >>= 1) d += __shfl_xor(d, m, 64);
    if (lane == 0) orow[idx] = d + bc[t * 20000 + idx];
  }
}

extern "C" void kernel_launch(void* const* d_in, const int* in_sizes, int n_in,
                              void* d_out, int out_size, void* d_ws, size_t ws_size,
                              hipStream_t stream) {
  const int* iv = (const int*)d_in[1];
  const int* cv = (const int*)d_in[2];
  const float* emb = (const float*)d_in[3];
  const float* Wih = (const float*)d_in[4];
  const float* Whh = (const float*)d_in[5];
  const float* bih = (const float*)d_in[6];
  const float* bhh = (const float*)d_in[7];
  const float* mWih = (const float*)d_in[8];
  const float* mWhh = (const float*)d_in[9];
  const float* mbih = (const float*)d_in[10];
  const float* mbhh = (const float*)d_in[11];
  const float* Wnew = (const float*)d_in[12];
  const float* bnew = (const float*)d_in[13];
  const float* Wcopy = (const float*)d_in[14];
  const float* bcopy = (const float*)d_in[15];
  float* out = (float*)d_out;
  char* ws = (char*)d_ws;

  size_t o = 0;
  auto take = [&](size_t sz) { size_t r = o; o += sz; return r; };
  size_t BAR = take(256);        // 64 contiguous u32 flags
  size_t CM  = take(15360);
  size_t EBH = take(983040);
  size_t EBL = take(983040);
  size_t HPK = take(4063232);    // packed bf16 hi|lo task-h [31][2][64][256] u32
  size_t APK = take(1966080);    // packed bf16 hi|lo meta-h [1920][256] u32
  size_t GIX = take(15728640);   // fp32 gi_x [64 blk][30][64][32]
  size_t W1H = take(2621440);
  size_t W1L = take(2621440);
  size_t W2H = take(1572864);
  size_t W2L = take(1572864);
  size_t WNH = take(10289152);
  size_t WNL = take(10289152);
  if (ws_size < o) return;   // insufficient workspace: fail loudly via absmax

  hipFuncSetAttribute(reinterpret_cast<const void*>(k_rnn),
                      hipFuncAttributeMaxDynamicSharedMemorySize, RNN_LDS);

  hipMemsetAsync(ws + BAR, 0, 256, stream);

  k_pool<<<3840, 128, 0, stream>>>(iv, emb, (u16*)(ws + EBH), (u16*)(ws + EBL), (float*)(ws + CM));
  k_swz<<<3536, 256, 0, stream>>>(Wih, Whh, mWih, mWhh, Wnew,
                                  (u16*)(ws + W1H), (u16*)(ws + W1L),
                                  (u16*)(ws + W2H), (u16*)(ws + W2L),
                                  (u16*)(ws + WNH), (u16*)(ws + WNL));
  k_gix<<<64, 256, 0, stream>>>((const u16*)(ws + EBH), (const u16*)(ws + EBL),
                                (const u16*)(ws + W1H), (const u16*)(ws + W1L),
                                bih, bhh, (float*)(ws + GIX));
  k_rnn<<<NB_ + HELPERS_, 256, RNN_LDS, stream>>>(
      (const u16*)(ws + W1H), (const u16*)(ws + W1L),
      (const u16*)(ws + W2H), (const u16*)(ws + W2L),
      (const float*)(ws + GIX), bhh, mbih, mbhh,
      (const float*)(ws + CM),
      (u32*)(ws + HPK), (u32*)(ws + APK),
      (u32*)(ws + BAR),
      out + 38400000);
  k_gnew<<<2355, 256, 0, stream>>>((const u32*)(ws + APK),
                                   (const u16*)(ws + WNH), (const u16*)(ws + WNL),
                                   bnew, out);
  k_copy<<<3840, 256, 0, stream>>>((const u32*)(ws + HPK), cv, Wcopy, bcopy, out);
}

// Round 10
// 488.875 us; speedup vs baseline: 1.6619x; 1.1742x over previous
//
#include <hip/hip_runtime.h>

typedef unsigned short u16;
typedef unsigned int u32;
typedef unsigned long long u64;
typedef __attribute__((ext_vector_type(8))) short short8;
typedef __attribute__((ext_vector_type(4))) float f32x4;

#define NB_ 64
#define NHELP_ 6195   // 15 groups * (128 copy + 128 copy + 157 gnew)

static __device__ __forceinline__ f32x4 mfma16(short8 a, short8 b, f32x4 c) {
  return __builtin_amdgcn_mfma_f32_16x16x32_bf16(a, b, c, 0, 0, 0);
}

// split fp32 -> bf16 hi + bf16 lo  (x ~= hi + lo, residual ~2^-17 * |x|)
static __device__ __forceinline__ void split_bf16(float x, u16& hi, u16& lo) {
  unsigned u = __float_as_uint(x);
  unsigned r = (u + 0x7fffu + ((u >> 16) & 1u)) >> 16;
  hi = (u16)r;
  float fh = __uint_as_float(r << 16);
  float xl = x - fh;
  unsigned ul = __float_as_uint(xl);
  unsigned rl2 = (ul + 0x7fffu + ((ul >> 16) & 1u)) >> 16;
  lo = (u16)rl2;
}

// write-through publication store to the coherence point (proven r1-r9)
static __device__ __forceinline__ void astore(u32* p, u32 v) {
  __hip_atomic_store(p, v, __ATOMIC_RELAXED, __HIP_MEMORY_SCOPE_AGENT);
}
static __device__ __forceinline__ void unpack8(const uint4& a, const uint4& b,
                                               short8& h, short8& l) {
  u32 wb[8] = {a.x, a.y, a.z, a.w, b.x, b.y, b.z, b.w};
  #pragma unroll
  for (int j = 0; j < 8; ++j) {
    h[j] = (short)(wb[j] & 0xffffu);
    l[j] = (short)(wb[j] >> 16);
  }
}
static __device__ __forceinline__ float unpack_hl(u32 pk) {
  return __uint_as_float((pk & 0xffffu) << 16) + __uint_as_float(pk & 0xffff0000u);
}
static __device__ __forceinline__ void vload8(const u32* p, short8& h, short8& l) {
  uint4 a = *(const uint4*)p;
  uint4 b = *(const uint4*)(p + 4);
  unpack8(a, b, h, l);
}

// ---------------- pooling: emb gather + mean over valid items ----------------
__global__ __launch_bounds__(128) void k_pool(const int* __restrict__ iv,
                                              const float* __restrict__ emb,
                                              u16* __restrict__ ebh, u16* __restrict__ ebl,
                                              float* __restrict__ cm) {
  int u = blockIdx.x;             // u = (s*2+t)*64+b
  int s = u >> 7;
  int t = (u >> 6) & 1;
  int b = u & 63;
  int d = threadIdx.x;
  const int ibase = ((t * 64 + b) * 30 + s) * 12;
  float sum = 0.f;
  int cnt = 0;
  for (int k = 0; k < 12; ++k) {
    int idx = iv[ibase + k];
    if (idx > 0) { cnt++; sum += emb[(size_t)idx * 128 + d]; }
  }
  float den = (cnt > 0) ? (float)cnt : 1.f;
  float v = sum / den;
  u16 hi, lo; split_bf16(v, hi, lo);
  ebh[(size_t)u * 128 + d] = hi;
  ebl[(size_t)u * 128 + d] = lo;
  if (d == 0) cm[u] = (cnt > 0) ? 1.f : 0.f;
}

// ---------------- weight swizzle into MFMA B-fragment layout ----------------
// B-frag (16x16x32): lane l holds B[k=(l>>4)*8+j][n=l&15], j=0..7
// w1: 64 blk * 20 ks * 2 nt; ks 0..7 WihH(K=256), 8..15 Whh(K=256), 16..19 WihX(K=128)
// w2: 64 blk * 24 ks; ks 0..7 mWih OWN task (t1=blk>>5), 8..15 mWih other task, 16..23 mWhh
__global__ __launch_bounds__(256) void k_swz(const float* __restrict__ Wih,
                                             const float* __restrict__ Whh,
                                             const float* __restrict__ mWih,
                                             const float* __restrict__ mWhh,
                                             const float* __restrict__ Wnew,
                                             u16* __restrict__ w1h, u16* __restrict__ w1l,
                                             u16* __restrict__ w2h, u16* __restrict__ w2l,
                                             u16* __restrict__ wnh, u16* __restrict__ wnl) {
  int gu = blockIdx.x * 4 + (threadIdx.x >> 6);
  int lane = threadIdx.x & 63;
  int ko = (lane >> 4) * 8;
  int cl = lane & 15;
  float src[8];
  if (gu < 2560) {
    int blk = gu / 40, r = gu % 40, ksIdx = r >> 1, nt = r & 1;
    int t = blk >> 5, hd0 = (blk & 31) * 8;
    int c = nt * 16 + cl;
    if (c < 24) {
      int gc = (c < 8) ? (hd0 + c) : (c < 16) ? (256 + hd0 + (c - 8)) : (512 + hd0 + (c - 16));
      const float* wrow; int kk;
      if (ksIdx < 8)       { wrow = Wih + (size_t)(t * 768 + gc) * 384 + 128; kk = ksIdx * 32 + ko; }
      else if (ksIdx < 16) { wrow = Whh + (size_t)(t * 768 + gc) * 256;       kk = (ksIdx - 8) * 32 + ko; }
      else                 { wrow = Wih + (size_t)(t * 768 + gc) * 384;       kk = (ksIdx - 16) * 32 + ko; }
      #pragma unroll
      for (int j = 0; j < 8; ++j) src[j] = wrow[kk + j];
    } else {
      #pragma unroll
      for (int j = 0; j < 8; ++j) src[j] = 0.f;
    }
    int off = gu * 512 + lane * 8;
    #pragma unroll
    for (int j = 0; j < 8; ++j) { u16 h, l; split_bf16(src[j], h, l); w1h[off + j] = h; w1l[off + j] = l; }
  } else if (gu < 4096) {
    int g2 = gu - 2560;
    int blk = g2 / 24, ksIdx = g2 % 24;
    int t1 = blk >> 5;
    int hd0 = blk * 4;
    int c = cl;
    if (c < 12) {
      int gc = (c < 4) ? (hd0 + c) : (c < 8) ? (256 + hd0 + (c - 4)) : (512 + hd0 + (c - 8));
      if (ksIdx < 16) {
        int chunk = (ksIdx < 8) ? (t1 * 8 + ksIdx) : ((1 - t1) * 8 + (ksIdx - 8));
        int kk = chunk * 32 + ko;
        #pragma unroll
        for (int j = 0; j < 8; ++j) src[j] = mWih[(size_t)gc * 512 + kk + j];
      } else {
        int kk = (ksIdx - 16) * 32 + ko;
        #pragma unroll
        for (int j = 0; j < 8; ++j) src[j] = mWhh[(size_t)gc * 256 + kk + j];
      }
    } else {
      #pragma unroll
      for (int j = 0; j < 8; ++j) src[j] = 0.f;
    }
    int off = g2 * 512 + lane * 8;
    #pragma unroll
    for (int j = 0; j < 8; ++j) { u16 h, l; split_bf16(src[j], h, l); w2h[off + j] = h; w2l[off + j] = l; }
  } else if (gu < 14144) {
    int g3 = gu - 4096;
    int gnt = g3 >> 3, ks = g3 & 7;
    int col = gnt * 16 + cl;
    if (col < 20000) {
      int kk = ks * 32 + ko;
      #pragma unroll
      for (int j = 0; j < 8; ++j) src[j] = Wnew[(size_t)col * 256 + kk + j];
    } else {
      #pragma unroll
      for (int j = 0; j < 8; ++j) src[j] = 0.f;
    }
    int off = g3 * 512 + lane * 8;
    #pragma unroll
    for (int j = 0; j < 8; ++j) { u16 h, l; split_bf16(src[j], h, l); wnh[off + j] = h; wnl[off + j] = l; }
  }
}

// ---------------- gi_x precompute: gi_x = x @ WihX^T (+bias folds) ----------------
// layout: gix[blk][s][row 0..63][32]: cols 0..15 = r,z (+bih+bhh), 16..23 = n (+bih)
__global__ __launch_bounds__(256) void k_gix(const u16* __restrict__ ebh, const u16* __restrict__ ebl,
                                             const u16* __restrict__ w1h, const u16* __restrict__ w1l,
                                             const float* __restrict__ bih, const float* __restrict__ bhh,
                                             float* __restrict__ gix) {
  int blk = blockIdx.x;
  int t1 = blk >> 5, hd1 = (blk & 31) * 8;
  int tid = threadIdx.x, lane = tid & 63, w = tid >> 6;
  int arow = w * 16 + (lane & 15);
  int ko = (lane >> 4) * 8;
  __shared__ u16 lwh[4096], lwl[4096];
  {
    const uint4* sh = (const uint4*)(w1h + ((size_t)blk * 40 + 32) * 512);
    const uint4* sl = (const uint4*)(w1l + ((size_t)blk * 40 + 32) * 512);
    uint4* dh = (uint4*)lwh; uint4* dl = (uint4*)lwl;
    for (int i = tid; i < 512; i += 256) { dh[i] = sh[i]; dl[i] = sl[i]; }
  }
  int c = lane & 15;
  float brz, bn = 0.f;
  {
    int gc = (c < 8) ? (hd1 + c) : (256 + hd1 + (c - 8));
    brz = bih[t1 * 768 + gc] + bhh[t1 * 768 + gc];
    if (c < 8) bn = bih[t1 * 768 + 512 + hd1 + c];
  }
  __syncthreads();
  for (int s = 0; s < 30; ++s) {
    f32x4 a3[2];
    a3[0] = (f32x4){0.f, 0.f, 0.f, 0.f};
    a3[1] = (f32x4){0.f, 0.f, 0.f, 0.f};
    const u16* Xh = ebh + (size_t)((s * 2 + t1) * 64 + arow) * 128;
    const u16* Xl = ebl + (size_t)((s * 2 + t1) * 64 + arow) * 128;
    #pragma unroll
    for (int k = 0; k < 4; ++k) {
      short8 xh = *(const short8*)(Xh + k * 32 + ko);
      short8 xl = *(const short8*)(Xl + k * 32 + ko);
      #pragma unroll
      for (int nt = 0; nt < 2; ++nt) {
        short8 bh = *(const short8*)(lwh + (k * 2 + nt) * 512 + lane * 8);
        short8 bl = *(const short8*)(lwl + (k * 2 + nt) * 512 + lane * 8);
        a3[nt] = mfma16(xh, bh, a3[nt]);
        a3[nt] = mfma16(xl, bh, a3[nt]);
        a3[nt] = mfma16(xh, bl, a3[nt]);
      }
    }
    float* grow = gix + (size_t)(blk * 30 + s) * 64 * 32;
    #pragma unroll
    for (int i = 0; i < 4; ++i) {
      int r = w * 16 + (lane >> 4) * 4 + i;
      grow[r * 32 + c] = a3[0][i] + brz;
      if (c < 8) grow[r * 32 + 16 + c] = a3[1][i] + bn;
    }
  }
}

// ---------------- barrier helpers ----------------
static __device__ __forceinline__ void bar_arrive(u32* slots, int blk, int epoch) {
  __syncthreads();              // all waves' publication stores drained
  if (threadIdx.x == 0) astore(slots + blk, (u32)epoch);
}
static __device__ __forceinline__ void bar_wait(u32* slots, int epoch) {
  int lane = threadIdx.x & 63;
  u32 v;
  for (;;) {
    asm volatile("global_load_dword %0, %1, off sc0 sc1\n\ts_waitcnt vmcnt(0)"
                 : "=v"(v) : "v"(slots + lane) : "memory");
    if ((int)v >= epoch) break;
  }
}
// throttled helper poll: wave 0 polls all 64 flags, whole block releases via barrier
static __device__ __forceinline__ void helper_wait(u32* slots, int target) {
  if (threadIdx.x < 64) {
    u32 v;
    for (;;) {
      asm volatile("global_load_dword %0, %1, off sc0 sc1\n\ts_waitcnt vmcnt(0)"
                   : "=v"(v) : "v"(slots + threadIdx.x) : "memory");
      if (__all((int)v >= target)) break;
      __builtin_amdgcn_s_sleep(15);
      __builtin_amdgcn_s_sleep(15);
    }
  }
  __syncthreads();
}

// dynamic LDS layout (bytes):
//   [0)       w1h  32 units * 1024 = 32768
//   [32768)   w1l  32768
//   [65536)   w2h  24 units * 1024 = 24576
//   [90112)   w2l  24576            -> 114688
//   [114688)  ls_rz float[4][16][16] 4096
//   [118784)  ls_gi float[4][16][8]  2048
//   [120832)  ls_gh float[4][16][8]  2048
//   [122880)  ls_cm float[30][64]    7680  -> total 130560
#define RNN_LDS 130560

// Mega kernel: blocks 0..63 = persistent GRU recurrence (r9 structure, apk s-major);
// blocks 64.. = self-scheduling epilogue helpers ordered by readiness epoch:
//   group g (0..14): 128 copy blocks (s=2g), 128 copy blocks (s=2g+1), 157 gnew blocks (q=g)
__global__ __launch_bounds__(256, 1) void k_mega(
    const u16* __restrict__ w1h, const u16* __restrict__ w1l,
    const u16* __restrict__ w2h, const u16* __restrict__ w2l,
    const float* __restrict__ gix,
    const float* __restrict__ bhh,
    const float* __restrict__ mbih, const float* __restrict__ mbhh,
    const float* __restrict__ cm,
    u32* __restrict__ hpk,       // packed (hi|lo<<16) task-h   [31][2][64][256]
    u32* __restrict__ apk,       // packed (hi|lo<<16) meta-h   [30][64][256]  (S-MAJOR: s*64+b)
    u32* slots,
    const u16* __restrict__ wnh, const u16* __restrict__ wnl,
    const float* __restrict__ bnew,
    const int* __restrict__ cv,
    const float* __restrict__ wc,
    const float* __restrict__ bc,
    float* __restrict__ out) {

  if (blockIdx.x >= NB_) {
    // ================= helper blocks =================
    int h = blockIdx.x - NB_;
    int g = h / 413, r = h % 413;
    int tid = threadIdx.x, lane = tid & 63, w = tid >> 6;
    int ko = (lane >> 4) * 8;
    if (r < 256) {
      // ---- copy-score block: zero own row, wait for hpk[s+1], scatter ----
      int s = 2 * g + (r >= 128);
      int rr = r & 127;
      int t = rr >> 6, b = rr & 63;
      float* orow = out + (size_t)(1 + t) * 38400000 + (size_t)(b * 30 + s) * 20000;
      f32x4 z4 = {0.f, 0.f, 0.f, 0.f};
      f32x4* zp = (f32x4*)orow;
      for (int i = tid; i < 5000; i += 256)
        __builtin_nontemporal_store(z4, zp + i);
      helper_wait(slots, 2 * s + 1);   // also drains zero-stores via the barrier
      const u32* hp = hpk + (size_t)(((s + 1) * 2 + t) * 64 + b) * 256;
      uint4 hq = *(const uint4*)(hp + lane * 4);
      float4 h4;
      h4.x = unpack_hl(hq.x); h4.y = unpack_hl(hq.y);
      h4.z = unpack_hl(hq.z); h4.w = unpack_hl(hq.w);
      int base = ((t * 64 + b) * 30 + s) * 20;
      for (int c = w; c < 20; c += 4) {
        int idx = cv[base + c];
        const float* wr = wc + ((size_t)t * 20000 + idx) * 256;
        float4 w4 = *(const float4*)(wr + lane * 4);
        float d = h4.x * w4.x + h4.y * w4.y + h4.z * w4.z + h4.w * w4.w;
        #pragma unroll
        for (int m = 32; m >= 1; m >>= 1) d += __shfl_xor(d, m, 64);
        if (lane == 0) orow[idx] = d + bc[t * 20000 + idx];
      }
    } else {
      // ---- gnew block: tile q over apk rows (s-major), nb over 128 cols ----
      int q = g, nb = r - 256;
      helper_wait(slots, 4 * q + 4);   // apk rows s=2q,2q+1 published
      f32x4 acc[2][8];
      #pragma unroll
      for (int mi = 0; mi < 2; ++mi)
        #pragma unroll
        for (int nt = 0; nt < 8; ++nt) acc[mi][nt] = (f32x4){0.f, 0.f, 0.f, 0.f};
      #pragma unroll
      for (int ks = 0; ks < 8; ++ks) {
        short8 ah[2], al[2];
        #pragma unroll
        for (int mi = 0; mi < 2; ++mi) {
          int rrow = q * 128 + (w * 2 + mi) * 16 + (lane & 15);
          vload8(apk + (size_t)rrow * 256 + ks * 32 + ko, ah[mi], al[mi]);
        }
        #pragma unroll
        for (int nt = 0; nt < 8; ++nt) {
          int un = (nb * 8 + nt) * 8 + ks;
          short8 bh = *(const short8*)(wnh + (size_t)un * 512 + lane * 8);
          short8 bl = *(const short8*)(wnl + (size_t)un * 512 + lane * 8);
          #pragma unroll
          for (int mi = 0; mi < 2; ++mi) {
            acc[mi][nt] = mfma16(ah[mi], bh, acc[mi][nt]);
            acc[mi][nt] = mfma16(al[mi], bh, acc[mi][nt]);
            acc[mi][nt] = mfma16(ah[mi], bl, acc[mi][nt]);
          }
        }
      }
      #pragma unroll
      for (int mi = 0; mi < 2; ++mi)
        #pragma unroll
        for (int nt = 0; nt < 8; ++nt) {
          int col = nb * 128 + nt * 16 + (lane & 15);
          if (col < 20000) {
            float bn = bnew[col];
            #pragma unroll
            for (int i = 0; i < 4; ++i) {
              int rrow = q * 128 + (w * 2 + mi) * 16 + (lane >> 4) * 4 + i;
              int sA = rrow >> 6, bA = rrow & 63;
              out[(size_t)(bA * 30 + sA) * 20000 + col] = acc[mi][nt][i] + bn;
            }
          }
        }
    }
    return;
  }

  // ================= recurrence blocks (r9 structure) =================
  extern __shared__ char smem[];
  u16* lw1h = (u16*)smem;
  u16* lw1l = (u16*)(smem + 32768);
  u16* lw2h = (u16*)(smem + 65536);
  u16* lw2l = (u16*)(smem + 90112);
  float* ls_rz = (float*)(smem + 114688);
  float* ls_gi = (float*)(smem + 118784);
  float* ls_gh = (float*)(smem + 120832);
  float* ls_cm = (float*)(smem + 122880);

  const int blk = blockIdx.x;
  const int tid = threadIdx.x;
  const int lane = tid & 63;
  const int w = tid >> 6;
  const int t1 = blk >> 5;
  const int hd1 = (blk & 31) * 8;
  const int hd2 = blk * 4;
  const int arow = w * 16 + (lane & 15);
  const int ko = (lane >> 4) * 8;
  int epoch = 0;

  // one-time: weights -> LDS, cm -> LDS
  {
    const uint4* s1h = (const uint4*)(w1h + (size_t)blk * 40 * 512);
    const uint4* s1l = (const uint4*)(w1l + (size_t)blk * 40 * 512);
    uint4* d1h = (uint4*)lw1h; uint4* d1l = (uint4*)lw1l;
    for (int i = tid; i < 2048; i += 256) { d1h[i] = s1h[i]; d1l[i] = s1l[i]; }
    const uint4* s2h = (const uint4*)(w2h + (size_t)blk * 24 * 512);
    const uint4* s2l = (const uint4*)(w2l + (size_t)blk * 24 * 512);
    uint4* d2h = (uint4*)lw2h; uint4* d2l = (uint4*)lw2l;
    for (int i = tid; i < 1536; i += 256) { d2h[i] = s2h[i]; d2l[i] = s2l[i]; }
    for (int i = tid; i < 1920; i += 256) ls_cm[i] = cm[((i >> 6) * 2 + t1) * 64 + (i & 63)];
  }
  // hoisted per-thread constants
  const int cc = lane & 15;
  float bhhn = (cc < 8) ? bhh[t1 * 768 + 512 + hd1 + cc] : 0.f;
  float mrz_b = 0.f, mgi_b = 0.f, mgh_b = 0.f;
  if (cc < 8) {
    int gc = (cc < 4) ? (hd2 + cc) : (256 + hd2 + (cc - 4));
    mrz_b = mbih[gc] + mbhh[gc];
  } else if (cc < 12) {
    int gn = 512 + hd2 + (cc - 8);
    mgi_b = mbih[gn];
    mgh_b = mbhh[gn];
  }

  // gi_x prefetch registers
  float gq[8];
  {
    const float* grow = gix + (size_t)(blk * 30 + 0) * 2048;
    #pragma unroll
    for (int i = 0; i < 4; ++i) {
      int r = w * 16 + (lane >> 4) * 4 + i;
      gq[i]     = grow[r * 32 + cc];
      gq[4 + i] = grow[r * 32 + 16 + (cc & 7)];
    }
  }
  __syncthreads();

  short8 ah1[8], al1[8];   // apk[s-1] (G1; reused by m2)
  short8 xh2[8], xl2[8];   // own-task hpk[s] (loaded phase-2 of s-1; used by a2s)
  f32x4 a2s[2];            // Whh @ h_task, precomputed at end of previous iteration
  a2s[0] = (f32x4){0.f, 0.f, 0.f, 0.f};
  a2s[1] = (f32x4){0.f, 0.f, 0.f, 0.f};
  float hold0 = 0.f, hold1 = 0.f;
  float hm_reg = 0.f;

  for (int s = 0; s < 30; ++s) {
    // ---------- phase 1: task GRUs ----------
    f32x4 a1[2];
    a1[0] = (f32x4){0.f, 0.f, 0.f, 0.f};
    a1[1] = (f32x4){0.f, 0.f, 0.f, 0.f};
    if (s > 0) {
      bar_wait(slots, epoch);
      // apk s-major: 64 contiguous rows per step
      const u32* Ap = apk + (size_t)((s - 1) * 64 + arow) * 256 + ko;
      uint4 ra[16];
      #pragma unroll
      for (int k = 0; k < 8; ++k) {
        ra[2 * k]     = *(const uint4*)(Ap + k * 32);
        ra[2 * k + 1] = *(const uint4*)(Ap + k * 32 + 4);
      }
      #pragma unroll
      for (int k = 0; k < 8; ++k) {
        unpack8(ra[2 * k], ra[2 * k + 1], ah1[k], al1[k]);
        #pragma unroll
        for (int nt = 0; nt < 2; ++nt) {
          short8 bh = *(const short8*)(lw1h + (k * 2 + nt) * 512 + lane * 8);
          short8 bl = *(const short8*)(lw1l + (k * 2 + nt) * 512 + lane * 8);
          a1[nt] = mfma16(ah1[k], bh, a1[nt]);
          a1[nt] = mfma16(al1[k], bh, a1[nt]);
          a1[nt] = mfma16(ah1[k], bl, a1[nt]);
        }
      }
    }
    // gates -> LDS (per-wave slices; intra-wave ordering via lgkmcnt)
    #pragma unroll
    for (int i = 0; i < 4; ++i) {
      int rl = (lane >> 4) * 4 + i;
      ls_rz[(w * 16 + rl) * 16 + cc] = a1[0][i] + a2s[0][i] + gq[i];
      if (cc < 8) {
        ls_gi[(w * 16 + rl) * 8 + cc] = a1[1][i] + gq[4 + i];
        ls_gh[(w * 16 + rl) * 8 + cc] = a2s[1][i] + bhhn;
      }
    }
    asm volatile("s_waitcnt lgkmcnt(0)" ::: "memory");
    {
      int item = lane;
      int rl = item >> 3, c = item & 7;
      float rv = ls_rz[(w * 16 + rl) * 16 + c], zv = ls_rz[(w * 16 + rl) * 16 + 8 + c];
      float gi = ls_gi[(w * 16 + rl) * 8 + c], gh = ls_gh[(w * 16 + rl) * 8 + c];
      float r = 1.f / (1.f + expf(-rv));
      float z = 1.f / (1.f + expf(-zv));
      float n = tanhf(gi + r * gh);
      int b = w * 16 + rl;
      float m = ls_cm[s * 64 + b];
      float hnew = (1.f - z) * n + z * hold0;
      float hout = (m > 0.5f) ? hnew : hold0;
      hold0 = hout;
      int oo = (((s + 1) * 2 + t1) * 64 + b) * 256 + hd1 + c;
      u16 xh, xl; split_bf16(hout, xh, xl);
      astore(hpk + oo, (u32)xh | ((u32)xl << 16));
    }
    {
      int item = 64 + lane;
      int rl = item >> 3, c = item & 7;
      float rv = ls_rz[(w * 16 + rl) * 16 + c], zv = ls_rz[(w * 16 + rl) * 16 + 8 + c];
      float gi = ls_gi[(w * 16 + rl) * 8 + c], gh = ls_gh[(w * 16 + rl) * 8 + c];
      float r = 1.f / (1.f + expf(-rv));
      float z = 1.f / (1.f + expf(-zv));
      float n = tanhf(gi + r * gh);
      int b = w * 16 + rl;
      float m = ls_cm[s * 64 + b];
      float hnew = (1.f - z) * n + z * hold1;
      float hout = (m > 0.5f) ? hnew : hold1;
      hold1 = hout;
      int oo = (((s + 1) * 2 + t1) * 64 + b) * 256 + hd1 + c;
      u16 xh, xl; split_bf16(hout, xh, xl);
      astore(hpk + oo, (u32)xh | ((u32)xl << 16));
    }
    ++epoch;
    bar_arrive(slots, blk, epoch);

    // ---- pre-poll local work: m2 (mWhh @ h_meta, regs) + gix prefetch ----
    f32x4 m1 = (f32x4){0.f, 0.f, 0.f, 0.f};
    f32x4 m2 = (f32x4){0.f, 0.f, 0.f, 0.f};
    if (s > 0) {
      #pragma unroll
      for (int k = 0; k < 8; ++k) {
        short8 bh = *(const short8*)(lw2h + (16 + k) * 512 + lane * 8);
        short8 bl = *(const short8*)(lw2l + (16 + k) * 512 + lane * 8);
        m2 = mfma16(ah1[k], bh, m2);
        m2 = mfma16(al1[k], bh, m2);
        m2 = mfma16(ah1[k], bl, m2);
      }
    }
    if (s < 29) {
      const float* grow = gix + (size_t)(blk * 30 + s + 1) * 2048;
      #pragma unroll
      for (int i = 0; i < 4; ++i) {
        int r = w * 16 + (lane >> 4) * 4 + i;
        gq[i]     = grow[r * 32 + cc];
        gq[4 + i] = grow[r * 32 + 16 + (cc & 7)];
      }
    }
    bar_wait(slots, epoch);

    // ---------- phase 2: meta GRU ----------
    {
      const u32* Hp = hpk + (size_t)(((s + 1) * 2 + t1) * 64 + arow) * 256 + ko;
      const u32* Hq = hpk + (size_t)(((s + 1) * 2 + (1 - t1)) * 64 + arow) * 256 + ko;
      uint4 rx[16], ry[16];
      #pragma unroll
      for (int k = 0; k < 8; ++k) {
        rx[2 * k]     = *(const uint4*)(Hp + k * 32);
        rx[2 * k + 1] = *(const uint4*)(Hp + k * 32 + 4);
        ry[2 * k]     = *(const uint4*)(Hq + k * 32);
        ry[2 * k + 1] = *(const uint4*)(Hq + k * 32 + 4);
      }
      #pragma unroll
      for (int k = 0; k < 8; ++k) {
        unpack8(rx[2 * k], rx[2 * k + 1], xh2[k], xl2[k]);
        short8 bh = *(const short8*)(lw2h + k * 512 + lane * 8);
        short8 bl = *(const short8*)(lw2l + k * 512 + lane * 8);
        m1 = mfma16(xh2[k], bh, m1);
        m1 = mfma16(xl2[k], bh, m1);
        m1 = mfma16(xh2[k], bl, m1);
      }
      #pragma unroll
      for (int k = 0; k < 8; ++k) {
        short8 yh, yl;
        unpack8(ry[2 * k], ry[2 * k + 1], yh, yl);
        short8 bh = *(const short8*)(lw2h + (8 + k) * 512 + lane * 8);
        short8 bl = *(const short8*)(lw2l + (8 + k) * 512 + lane * 8);
        m1 = mfma16(yh, bh, m1);
        m1 = mfma16(yl, bh, m1);
        m1 = mfma16(yh, bl, m1);
      }
    }
    #pragma unroll
    for (int i = 0; i < 4; ++i) {
      int rl = (lane >> 4) * 4 + i;
      if (cc < 8) {
        ls_rz[(w * 16 + rl) * 16 + cc] = m1[i] + m2[i] + mrz_b;
      } else if (cc < 12) {
        ls_gi[(w * 16 + rl) * 8 + (cc - 8)] = m1[i] + mgi_b;
        ls_gh[(w * 16 + rl) * 8 + (cc - 8)] = m2[i] + mgh_b;
      }
    }
    asm volatile("s_waitcnt lgkmcnt(0)" ::: "memory");
    {
      int rl = lane >> 2, c = lane & 3;
      float rv = ls_rz[(w * 16 + rl) * 16 + c], zv = ls_rz[(w * 16 + rl) * 16 + 4 + c];
      float gi = ls_gi[(w * 16 + rl) * 8 + c], gh = ls_gh[(w * 16 + rl) * 8 + c];
      float r = 1.f / (1.f + expf(-rv));
      float z = 1.f / (1.f + expf(-zv));
      float n = tanhf(gi + r * gh);
      int b = w * 16 + rl;
      int g2 = hd2 + c;
      float hmnew = (1.f - z) * n + z * hm_reg;
      hm_reg = hmnew;
      int ar = s * 64 + b;    // S-MAJOR
      u16 xh, xl; split_bf16(hmnew, xh, xl);
      astore(apk + ar * 256 + g2, (u32)xh | ((u32)xl << 16));
    }
    ++epoch;
    bar_arrive(slots, blk, epoch);

    // ---- pre-poll local work for next step: a2s = Whh @ h_task (regs) ----
    a2s[0] = (f32x4){0.f, 0.f, 0.f, 0.f};
    a2s[1] = (f32x4){0.f, 0.f, 0.f, 0.f};
    if (s < 29) {
      #pragma unroll
      for (int k = 0; k < 8; ++k) {
        #pragma unroll
        for (int nt = 0; nt < 2; ++nt) {
          short8 bh = *(const short8*)(lw1h + ((8 + k) * 2 + nt) * 512 + lane * 8);
          short8 bl = *(const short8*)(lw1l + ((8 + k) * 2 + nt) * 512 + lane * 8);
          a2s[nt] = mfma16(xh2[k], bh, a2s[nt]);
          a2s[nt] = mfma16(xl2[k], bh, a2s[nt]);
          a2s[nt] = mfma16(xh2[k], bl, a2s[nt]);
        }
      }
    }
  }
}

extern "C" void kernel_launch(void* const* d_in, const int* in_sizes, int n_in,
                              void* d_out, int out_size, void* d_ws, size_t ws_size,
                              hipStream_t stream) {
  const int* iv = (const int*)d_in[1];
  const int* cv = (const int*)d_in[2];
  const float* emb = (const float*)d_in[3];
  const float* Wih = (const float*)d_in[4];
  const float* Whh = (const float*)d_in[5];
  const float* bih = (const float*)d_in[6];
  const float* bhh = (const float*)d_in[7];
  const float* mWih = (const float*)d_in[8];
  const float* mWhh = (const float*)d_in[9];
  const float* mbih = (const float*)d_in[10];
  const float* mbhh = (const float*)d_in[11];
  const float* Wnew = (const float*)d_in[12];
  const float* bnew = (const float*)d_in[13];
  const float* Wcopy = (const float*)d_in[14];
  const float* bcopy = (const float*)d_in[15];
  float* out = (float*)d_out;
  char* ws = (char*)d_ws;

  size_t o = 0;
  auto take = [&](size_t sz) { size_t r = o; o += sz; return r; };
  size_t BAR = take(256);        // 64 contiguous u32 flags
  size_t CM  = take(15360);
  size_t EBH = take(983040);
  size_t EBL = take(983040);
  size_t HPK = take(4063232);    // packed bf16 hi|lo task-h [31][2][64][256] u32
  size_t APK = take(1966080);    // packed bf16 hi|lo meta-h [30][64][256] u32 (s-major)
  size_t GIX = take(15728640);   // fp32 gi_x [64 blk][30][64][32]
  size_t W1H = take(2621440);
  size_t W1L = take(2621440);
  size_t W2H = take(1572864);
  size_t W2L = take(1572864);
  size_t WNH = take(10289152);
  size_t WNL = take(10289152);
  if (ws_size < o) return;   // insufficient workspace: fail loudly via absmax

  hipFuncSetAttribute(reinterpret_cast<const void*>(k_mega),
                      hipFuncAttributeMaxDynamicSharedMemorySize, RNN_LDS);

  hipMemsetAsync(ws + BAR, 0, 256, stream);

  k_pool<<<3840, 128, 0, stream>>>(iv, emb, (u16*)(ws + EBH), (u16*)(ws + EBL), (float*)(ws + CM));
  k_swz<<<3536, 256, 0, stream>>>(Wih, Whh, mWih, mWhh, Wnew,
                                  (u16*)(ws + W1H), (u16*)(ws + W1L),
                                  (u16*)(ws + W2H), (u16*)(ws + W2L),
                                  (u16*)(ws + WNH), (u16*)(ws + WNL));
  k_gix<<<64, 256, 0, stream>>>((const u16*)(ws + EBH), (const u16*)(ws + EBL),
                                (const u16*)(ws + W1H), (const u16*)(ws + W1L),
                                bih, bhh, (float*)(ws + GIX));
  k_mega<<<NB_ + NHELP_, 256, RNN_LDS, stream>>>(
      (const u16*)(ws + W1H), (const u16*)(ws + W1L),
      (const u16*)(ws + W2H), (const u16*)(ws + W2L),
      (const float*)(ws + GIX), bhh, mbih, mbhh,
      (const float*)(ws + CM),
      (u32*)(ws + HPK), (u32*)(ws + APK),
      (u32*)(ws + BAR),
      (const u16*)(ws + WNH), (const u16*)(ws + WNL),
      bnew, cv, Wcopy, bcopy, out);
}

// Round 11
// 473.100 us; speedup vs baseline: 1.7173x; 1.0333x over previous
//
#include <hip/hip_runtime.h>

typedef unsigned short u16;
typedef unsigned int u32;
typedef unsigned long long u64;
typedef __attribute__((ext_vector_type(8))) short short8;
typedef __attribute__((ext_vector_type(4))) float f32x4;

#define NB_ 64
#define NHELP_ 6195   // 15 groups * (128 copy + 128 copy + 157 gnew)

static __device__ __forceinline__ f32x4 mfma16(short8 a, short8 b, f32x4 c) {
  return __builtin_amdgcn_mfma_f32_16x16x32_bf16(a, b, c, 0, 0, 0);
}

// split fp32 -> bf16 hi + bf16 lo  (x ~= hi + lo, residual ~2^-17 * |x|)
static __device__ __forceinline__ void split_bf16(float x, u16& hi, u16& lo) {
  unsigned u = __float_as_uint(x);
  unsigned r = (u + 0x7fffu + ((u >> 16) & 1u)) >> 16;
  hi = (u16)r;
  float fh = __uint_as_float(r << 16);
  float xl = x - fh;
  unsigned ul = __float_as_uint(xl);
  unsigned rl2 = (ul + 0x7fffu + ((ul >> 16) & 1u)) >> 16;
  lo = (u16)rl2;
}

// write-through publication store to the coherence point (proven r1-r10)
static __device__ __forceinline__ void astore(u32* p, u32 v) {
  __hip_atomic_store(p, v, __ATOMIC_RELAXED, __HIP_MEMORY_SCOPE_AGENT);
}
static __device__ __forceinline__ void unpack8(const uint4& a, const uint4& b,
                                               short8& h, short8& l) {
  u32 wb[8] = {a.x, a.y, a.z, a.w, b.x, b.y, b.z, b.w};
  #pragma unroll
  for (int j = 0; j < 8; ++j) {
    h[j] = (short)(wb[j] & 0xffffu);
    l[j] = (short)(wb[j] >> 16);
  }
}
static __device__ __forceinline__ float unpack_hl(u32 pk) {
  return __uint_as_float((pk & 0xffffu) << 16) + __uint_as_float(pk & 0xffff0000u);
}
static __device__ __forceinline__ void vload8(const u32* p, short8& h, short8& l) {
  uint4 a = *(const uint4*)p;
  uint4 b = *(const uint4*)(p + 4);
  unpack8(a, b, h, l);
}

// ---------------- prep: pooling (blocks 0..1919) + weight swizzle (1920..5455) ----------------
// pool: emb gather + mean; 2 units per 256-thread block
// swz B-frag (16x16x32): lane l holds B[k=(l>>4)*8+j][n=l&15], j=0..7
// w1: 64 blk * 20 ks * 2 nt; ks 0..7 WihH(K=256), 8..15 Whh(K=256), 16..19 WihX(K=128)
// w2: 64 blk * 24 ks; ks 0..7 mWih OWN task (t1=blk>>5), 8..15 mWih other task, 16..23 mWhh
__global__ __launch_bounds__(256) void k_prep(const int* __restrict__ iv,
                                              const float* __restrict__ emb,
                                              u16* __restrict__ ebh, u16* __restrict__ ebl,
                                              float* __restrict__ cm,
                                              const float* __restrict__ Wih,
                                              const float* __restrict__ Whh,
                                              const float* __restrict__ mWih,
                                              const float* __restrict__ mWhh,
                                              const float* __restrict__ Wnew,
                                              u16* __restrict__ w1h, u16* __restrict__ w1l,
                                              u16* __restrict__ w2h, u16* __restrict__ w2l,
                                              u16* __restrict__ wnh, u16* __restrict__ wnl) {
  if (blockIdx.x < 1920) {
    int u = blockIdx.x * 2 + (threadIdx.x >> 7);   // u = (s*2+t)*64+b
    int s = u >> 7;
    int t = (u >> 6) & 1;
    int b = u & 63;
    int d = threadIdx.x & 127;
    const int ibase = ((t * 64 + b) * 30 + s) * 12;
    float sum = 0.f;
    int cnt = 0;
    for (int k = 0; k < 12; ++k) {
      int idx = iv[ibase + k];
      if (idx > 0) { cnt++; sum += emb[(size_t)idx * 128 + d]; }
    }
    float den = (cnt > 0) ? (float)cnt : 1.f;
    float v = sum / den;
    u16 hi, lo; split_bf16(v, hi, lo);
    ebh[(size_t)u * 128 + d] = hi;
    ebl[(size_t)u * 128 + d] = lo;
    if (d == 0) cm[u] = (cnt > 0) ? 1.f : 0.f;
    return;
  }
  int gu = (blockIdx.x - 1920) * 4 + (threadIdx.x >> 6);
  int lane = threadIdx.x & 63;
  int ko = (lane >> 4) * 8;
  int cl = lane & 15;
  float src[8];
  if (gu < 2560) {
    int blk = gu / 40, r = gu % 40, ksIdx = r >> 1, nt = r & 1;
    int t = blk >> 5, hd0 = (blk & 31) * 8;
    int c = nt * 16 + cl;
    if (c < 24) {
      int gc = (c < 8) ? (hd0 + c) : (c < 16) ? (256 + hd0 + (c - 8)) : (512 + hd0 + (c - 16));
      const float* wrow; int kk;
      if (ksIdx < 8)       { wrow = Wih + (size_t)(t * 768 + gc) * 384 + 128; kk = ksIdx * 32 + ko; }
      else if (ksIdx < 16) { wrow = Whh + (size_t)(t * 768 + gc) * 256;       kk = (ksIdx - 8) * 32 + ko; }
      else                 { wrow = Wih + (size_t)(t * 768 + gc) * 384;       kk = (ksIdx - 16) * 32 + ko; }
      #pragma unroll
      for (int j = 0; j < 8; ++j) src[j] = wrow[kk + j];
    } else {
      #pragma unroll
      for (int j = 0; j < 8; ++j) src[j] = 0.f;
    }
    int off = gu * 512 + lane * 8;
    #pragma unroll
    for (int j = 0; j < 8; ++j) { u16 h, l; split_bf16(src[j], h, l); w1h[off + j] = h; w1l[off + j] = l; }
  } else if (gu < 4096) {
    int g2 = gu - 2560;
    int blk = g2 / 24, ksIdx = g2 % 24;
    int t1 = blk >> 5;
    int hd0 = blk * 4;
    int c = cl;
    if (c < 12) {
      int gc = (c < 4) ? (hd0 + c) : (c < 8) ? (256 + hd0 + (c - 4)) : (512 + hd0 + (c - 8));
      if (ksIdx < 16) {
        int chunk = (ksIdx < 8) ? (t1 * 8 + ksIdx) : ((1 - t1) * 8 + (ksIdx - 8));
        int kk = chunk * 32 + ko;
        #pragma unroll
        for (int j = 0; j < 8; ++j) src[j] = mWih[(size_t)gc * 512 + kk + j];
      } else {
        int kk = (ksIdx - 16) * 32 + ko;
        #pragma unroll
        for (int j = 0; j < 8; ++j) src[j] = mWhh[(size_t)gc * 256 + kk + j];
      }
    } else {
      #pragma unroll
      for (int j = 0; j < 8; ++j) src[j] = 0.f;
    }
    int off = g2 * 512 + lane * 8;
    #pragma unroll
    for (int j = 0; j < 8; ++j) { u16 h, l; split_bf16(src[j], h, l); w2h[off + j] = h; w2l[off + j] = l; }
  } else if (gu < 14144) {
    int g3 = gu - 4096;
    int gnt = g3 >> 3, ks = g3 & 7;
    int col = gnt * 16 + cl;
    if (col < 20000) {
      int kk = ks * 32 + ko;
      #pragma unroll
      for (int j = 0; j < 8; ++j) src[j] = Wnew[(size_t)col * 256 + kk + j];
    } else {
      #pragma unroll
      for (int j = 0; j < 8; ++j) src[j] = 0.f;
    }
    int off = g3 * 512 + lane * 8;
    #pragma unroll
    for (int j = 0; j < 8; ++j) { u16 h, l; split_bf16(src[j], h, l); wnh[off + j] = h; wnl[off + j] = l; }
  }
}

// ---------------- gi_x precompute: gi_x = x @ WihX^T (+bias folds) ----------------
// layout: gix[blk][s][row 0..63][32]: cols 0..15 = r,z (+bih+bhh), 16..23 = n (+bih)
__global__ __launch_bounds__(256) void k_gix(const u16* __restrict__ ebh, const u16* __restrict__ ebl,
                                             const u16* __restrict__ w1h, const u16* __restrict__ w1l,
                                             const float* __restrict__ bih, const float* __restrict__ bhh,
                                             float* __restrict__ gix) {
  int blk = blockIdx.x;
  int t1 = blk >> 5, hd1 = (blk & 31) * 8;
  int tid = threadIdx.x, lane = tid & 63, w = tid >> 6;
  int arow = w * 16 + (lane & 15);
  int ko = (lane >> 4) * 8;
  __shared__ u16 lwh[4096], lwl[4096];
  {
    const uint4* sh = (const uint4*)(w1h + ((size_t)blk * 40 + 32) * 512);
    const uint4* sl = (const uint4*)(w1l + ((size_t)blk * 40 + 32) * 512);
    uint4* dh = (uint4*)lwh; uint4* dl = (uint4*)lwl;
    for (int i = tid; i < 512; i += 256) { dh[i] = sh[i]; dl[i] = sl[i]; }
  }
  int c = lane & 15;
  float brz, bn = 0.f;
  {
    int gc = (c < 8) ? (hd1 + c) : (256 + hd1 + (c - 8));
    brz = bih[t1 * 768 + gc] + bhh[t1 * 768 + gc];
    if (c < 8) bn = bih[t1 * 768 + 512 + hd1 + c];
  }
  __syncthreads();
  for (int s = 0; s < 30; ++s) {
    f32x4 a3[2];
    a3[0] = (f32x4){0.f, 0.f, 0.f, 0.f};
    a3[1] = (f32x4){0.f, 0.f, 0.f, 0.f};
    const u16* Xh = ebh + (size_t)((s * 2 + t1) * 64 + arow) * 128;
    const u16* Xl = ebl + (size_t)((s * 2 + t1) * 64 + arow) * 128;
    #pragma unroll
    for (int k = 0; k < 4; ++k) {
      short8 xh = *(const short8*)(Xh + k * 32 + ko);
      short8 xl = *(const short8*)(Xl + k * 32 + ko);
      #pragma unroll
      for (int nt = 0; nt < 2; ++nt) {
        short8 bh = *(const short8*)(lwh + (k * 2 + nt) * 512 + lane * 8);
        short8 bl = *(const short8*)(lwl + (k * 2 + nt) * 512 + lane * 8);
        a3[nt] = mfma16(xh, bh, a3[nt]);
        a3[nt] = mfma16(xl, bh, a3[nt]);
        a3[nt] = mfma16(xh, bl, a3[nt]);
      }
    }
    float* grow = gix + (size_t)(blk * 30 + s) * 64 * 32;
    #pragma unroll
    for (int i = 0; i < 4; ++i) {
      int r = w * 16 + (lane >> 4) * 4 + i;
      grow[r * 32 + c] = a3[0][i] + brz;
      if (c < 8) grow[r * 32 + 16 + c] = a3[1][i] + bn;
    }
  }
}

// ---------------- barrier helpers ----------------
static __device__ __forceinline__ void bar_arrive(u32* slots, int blk, int epoch) {
  __syncthreads();              // all waves' publication stores drained
  if (threadIdx.x == 0) astore(slots + blk, (u32)epoch);
}
static __device__ __forceinline__ void bar_wait(u32* slots, int epoch) {
  int lane = threadIdx.x & 63;
  u32 v;
  for (;;) {
    asm volatile("global_load_dword %0, %1, off sc0 sc1\n\ts_waitcnt vmcnt(0)"
                 : "=v"(v) : "v"(slots + lane) : "memory");
    if ((int)v >= epoch) break;
  }
}
// helpers poll ONLY hprog (own cache line, written by rnn block 0) — keeps all
// helper traffic off the rnn flag lines.
static __device__ __forceinline__ void helper_wait(const u32* hprog, int target) {
  if (threadIdx.x == 0) {
    u32 v;
    for (;;) {
      asm volatile("global_load_dword %0, %1, off sc0 sc1\n\ts_waitcnt vmcnt(0)"
                   : "=v"(v) : "v"(hprog) : "memory");
      if ((int)v >= target) break;
      __builtin_amdgcn_s_sleep(15);
      __builtin_amdgcn_s_sleep(15);
    }
  }
  __syncthreads();
}

// dynamic LDS layout (bytes):
//   [0)       w1h  32 units * 1024 = 32768
//   [32768)   w1l  32768
//   [65536)   w2h  24 units * 1024 = 24576
//   [90112)   w2l  24576            -> 114688
//   [114688)  ls_rz float[4][16][16] 4096
//   [118784)  ls_gi float[4][16][8]  2048
//   [120832)  ls_gh float[4][16][8]  2048
//   [122880)  ls_cm float[30][64]    7680  -> total 130560
#define RNN_LDS 130560

// Mega kernel: blocks 0..63 = persistent GRU recurrence (apk s-major);
// blocks 64.. = self-scheduling epilogue helpers ordered by readiness epoch:
//   group g (0..14): 128 copy blocks (s=2g), 128 copy blocks (s=2g+1), 157 gnew blocks (q=g)
__global__ __launch_bounds__(256, 1) void k_mega(
    const u16* __restrict__ w1h, const u16* __restrict__ w1l,
    const u16* __restrict__ w2h, const u16* __restrict__ w2l,
    const float* __restrict__ gix,
    const float* __restrict__ bhh,
    const float* __restrict__ mbih, const float* __restrict__ mbhh,
    const float* __restrict__ cm,
    u32* __restrict__ hpk,       // packed (hi|lo<<16) task-h   [31][2][64][256]
    u32* __restrict__ apk,       // packed (hi|lo<<16) meta-h   [30][64][256]  (S-MAJOR: s*64+b)
    u32* slots,                  // [64] rnn flags; slots[64] = hprog (own line)
    const u16* __restrict__ wnh, const u16* __restrict__ wnl,
    const float* __restrict__ bnew,
    const int* __restrict__ cv,
    const float* __restrict__ wc,
    const float* __restrict__ bc,
    float* __restrict__ out) {
  u32* hprog = slots + 64;

  if (blockIdx.x >= NB_) {
    // ================= helper blocks =================
    int h = blockIdx.x - NB_;
    int g = h / 413, r = h % 413;
    int tid = threadIdx.x, lane = tid & 63, w = tid >> 6;
    int ko = (lane >> 4) * 8;
    if (r < 256) {
      // ---- copy-score block: zero own row, wait for hpk[s+1], scatter ----
      int s = 2 * g + (r >= 128);
      int rr = r & 127;
      int t = rr >> 6, b = rr & 63;
      float* orow = out + (size_t)(1 + t) * 38400000 + (size_t)(b * 30 + s) * 20000;
      f32x4 z4 = {0.f, 0.f, 0.f, 0.f};
      f32x4* zp = (f32x4*)orow;
      for (int i = tid; i < 5000; i += 256)
        __builtin_nontemporal_store(z4, zp + i);
      helper_wait(hprog, 2 * s + 1);   // also drains zero-stores via the barrier
      const u32* hp = hpk + (size_t)(((s + 1) * 2 + t) * 64 + b) * 256;
      uint4 hq = *(const uint4*)(hp + lane * 4);
      float4 h4;
      h4.x = unpack_hl(hq.x); h4.y = unpack_hl(hq.y);
      h4.z = unpack_hl(hq.z); h4.w = unpack_hl(hq.w);
      int base = ((t * 64 + b) * 30 + s) * 20;
      for (int c = w; c < 20; c += 4) {
        int idx = cv[base + c];
        const float* wr = wc + ((size_t)t * 20000 + idx) * 256;
        float4 w4 = *(const float4*)(wr + lane * 4);
        float d = h4.x * w4.x + h4.y * w4.y + h4.z * w4.z + h4.w * w4.w;
        #pragma unroll
        for (int m = 32; m >= 1; m >>= 1) d += __shfl_xor(d, m, 64);
        if (lane == 0) orow[idx] = d + bc[t * 20000 + idx];
      }
    } else {
      // ---- gnew block: tile q over apk rows (s-major), nb over 128 cols ----
      int q = g, nb = r - 256;
      helper_wait(hprog, 4 * q + 4);   // apk rows s=2q,2q+1 published
      f32x4 acc[2][8];
      #pragma unroll
      for (int mi = 0; mi < 2; ++mi)
        #pragma unroll
        for (int nt = 0; nt < 8; ++nt) acc[mi][nt] = (f32x4){0.f, 0.f, 0.f, 0.f};
      #pragma unroll
      for (int ks = 0; ks < 8; ++ks) {
        short8 ah[2], al[2];
        #pragma unroll
        for (int mi = 0; mi < 2; ++mi) {
          int rrow = q * 128 + (w * 2 + mi) * 16 + (lane & 15);
          vload8(apk + (size_t)rrow * 256 + ks * 32 + ko, ah[mi], al[mi]);
        }
        #pragma unroll
        for (int nt = 0; nt < 8; ++nt) {
          int un = (nb * 8 + nt) * 8 + ks;
          short8 bh = *(const short8*)(wnh + (size_t)un * 512 + lane * 8);
          short8 bl = *(const short8*)(wnl + (size_t)un * 512 + lane * 8);
          #pragma unroll
          for (int mi = 0; mi < 2; ++mi) {
            acc[mi][nt] = mfma16(ah[mi], bh, acc[mi][nt]);
            acc[mi][nt] = mfma16(al[mi], bh, acc[mi][nt]);
            acc[mi][nt] = mfma16(ah[mi], bl, acc[mi][nt]);
          }
        }
      }
      #pragma unroll
      for (int mi = 0; mi < 2; ++mi)
        #pragma unroll
        for (int nt = 0; nt < 8; ++nt) {
          int col = nb * 128 + nt * 16 + (lane & 15);
          if (col < 20000) {
            float bn = bnew[col];
            #pragma unroll
            for (int i = 0; i < 4; ++i) {
              int rrow = q * 128 + (w * 2 + mi) * 16 + (lane >> 4) * 4 + i;
              int sA = rrow >> 6, bA = rrow & 63;
              out[(size_t)(bA * 30 + sA) * 20000 + col] = acc[mi][nt][i] + bn;
            }
          }
        }
    }
    return;
  }

  // ================= recurrence blocks =================
  extern __shared__ char smem[];
  u16* lw1h = (u16*)smem;
  u16* lw1l = (u16*)(smem + 32768);
  u16* lw2h = (u16*)(smem + 65536);
  u16* lw2l = (u16*)(smem + 90112);
  float* ls_rz = (float*)(smem + 114688);
  float* ls_gi = (float*)(smem + 118784);
  float* ls_gh = (float*)(smem + 120832);
  float* ls_cm = (float*)(smem + 122880);

  const int blk = blockIdx.x;
  const int tid = threadIdx.x;
  const int lane = tid & 63;
  const int w = tid >> 6;
  const int t1 = blk >> 5;
  const int hd1 = (blk & 31) * 8;
  const int hd2 = blk * 4;
  const int arow = w * 16 + (lane & 15);
  const int ko = (lane >> 4) * 8;
  int epoch = 0;

  // one-time: weights -> LDS, cm -> LDS
  {
    const uint4* s1h = (const uint4*)(w1h + (size_t)blk * 40 * 512);
    const uint4* s1l = (const uint4*)(w1l + (size_t)blk * 40 * 512);
    uint4* d1h = (uint4*)lw1h; uint4* d1l = (uint4*)lw1l;
    for (int i = tid; i < 2048; i += 256) { d1h[i] = s1h[i]; d1l[i] = s1l[i]; }
    const uint4* s2h = (const uint4*)(w2h + (size_t)blk * 24 * 512);
    const uint4* s2l = (const uint4*)(w2l + (size_t)blk * 24 * 512);
    uint4* d2h = (uint4*)lw2h; uint4* d2l = (uint4*)lw2l;
    for (int i = tid; i < 1536; i += 256) { d2h[i] = s2h[i]; d2l[i] = s2l[i]; }
    for (int i = tid; i < 1920; i += 256) ls_cm[i] = cm[((i >> 6) * 2 + t1) * 64 + (i & 63)];
  }
  // hoisted per-thread constants
  const int cc = lane & 15;
  float bhhn = (cc < 8) ? bhh[t1 * 768 + 512 + hd1 + cc] : 0.f;
  float mrz_b = 0.f, mgi_b = 0.f, mgh_b = 0.f;
  if (cc < 8) {
    int gc = (cc < 4) ? (hd2 + cc) : (256 + hd2 + (cc - 4));
    mrz_b = mbih[gc] + mbhh[gc];
  } else if (cc < 12) {
    int gn = 512 + hd2 + (cc - 8);
    mgi_b = mbih[gn];
    mgh_b = mbhh[gn];
  }

  // gi_x prefetch registers
  float gq[8];
  {
    const float* grow = gix + (size_t)(blk * 30 + 0) * 2048;
    #pragma unroll
    for (int i = 0; i < 4; ++i) {
      int r = w * 16 + (lane >> 4) * 4 + i;
      gq[i]     = grow[r * 32 + cc];
      gq[4 + i] = grow[r * 32 + 16 + (cc & 7)];
    }
  }
  __syncthreads();

  short8 ah1[8], al1[8];   // apk[s-1] (G1; reused by m2)
  short8 xh2[8], xl2[8];   // own-task hpk[s] (loaded phase-2 of s-1; used by a2s)
  f32x4 a2s[2];            // Whh @ h_task, precomputed at end of previous iteration
  a2s[0] = (f32x4){0.f, 0.f, 0.f, 0.f};
  a2s[1] = (f32x4){0.f, 0.f, 0.f, 0.f};
  float hold0 = 0.f, hold1 = 0.f;
  float hm_reg = 0.f;

  for (int s = 0; s < 30; ++s) {
    // ---------- phase 1: task GRUs ----------
    f32x4 a1[2];
    a1[0] = (f32x4){0.f, 0.f, 0.f, 0.f};
    a1[1] = (f32x4){0.f, 0.f, 0.f, 0.f};
    if (s > 0) {
      bar_wait(slots, epoch);
      if (blk == 0 && tid == 0) astore(hprog, (u32)epoch);   // all-arrived(epoch) proven
      // apk s-major: 64 contiguous rows per step
      const u32* Ap = apk + (size_t)((s - 1) * 64 + arow) * 256 + ko;
      uint4 ra[16];
      #pragma unroll
      for (int k = 0; k < 8; ++k) {
        ra[2 * k]     = *(const uint4*)(Ap + k * 32);
        ra[2 * k + 1] = *(const uint4*)(Ap + k * 32 + 4);
      }
      #pragma unroll
      for (int k = 0; k < 8; ++k) {
        unpack8(ra[2 * k], ra[2 * k + 1], ah1[k], al1[k]);
        #pragma unroll
        for (int nt = 0; nt < 2; ++nt) {
          short8 bh = *(const short8*)(lw1h + (k * 2 + nt) * 512 + lane * 8);
          short8 bl = *(const short8*)(lw1l + (k * 2 + nt) * 512 + lane * 8);
          a1[nt] = mfma16(ah1[k], bh, a1[nt]);
          a1[nt] = mfma16(al1[k], bh, a1[nt]);
          a1[nt] = mfma16(ah1[k], bl, a1[nt]);
        }
      }
    }
    // gates -> LDS (per-wave slices; intra-wave ordering via lgkmcnt)
    #pragma unroll
    for (int i = 0; i < 4; ++i) {
      int rl = (lane >> 4) * 4 + i;
      ls_rz[(w * 16 + rl) * 16 + cc] = a1[0][i] + a2s[0][i] + gq[i];
      if (cc < 8) {
        ls_gi[(w * 16 + rl) * 8 + cc] = a1[1][i] + gq[4 + i];
        ls_gh[(w * 16 + rl) * 8 + cc] = a2s[1][i] + bhhn;
      }
    }
    asm volatile("s_waitcnt lgkmcnt(0)" ::: "memory");
    {
      int item = lane;
      int rl = item >> 3, c = item & 7;
      float rv = ls_rz[(w * 16 + rl) * 16 + c], zv = ls_rz[(w * 16 + rl) * 16 + 8 + c];
      float gi = ls_gi[(w * 16 + rl) * 8 + c], gh = ls_gh[(w * 16 + rl) * 8 + c];
      float r = 1.f / (1.f + expf(-rv));
      float z = 1.f / (1.f + expf(-zv));
      float n = tanhf(gi + r * gh);
      int b = w * 16 + rl;
      float m = ls_cm[s * 64 + b];
      float hnew = (1.f - z) * n + z * hold0;
      float hout = (m > 0.5f) ? hnew : hold0;
      hold0 = hout;
      int oo = (((s + 1) * 2 + t1) * 64 + b) * 256 + hd1 + c;
      u16 xh, xl; split_bf16(hout, xh, xl);
      astore(hpk + oo, (u32)xh | ((u32)xl << 16));
    }
    {
      int item = 64 + lane;
      int rl = item >> 3, c = item & 7;
      float rv = ls_rz[(w * 16 + rl) * 16 + c], zv = ls_rz[(w * 16 + rl) * 16 + 8 + c];
      float gi = ls_gi[(w * 16 + rl) * 8 + c], gh = ls_gh[(w * 16 + rl) * 8 + c];
      float r = 1.f / (1.f + expf(-rv));
      float z = 1.f / (1.f + expf(-zv));
      float n = tanhf(gi + r * gh);
      int b = w * 16 + rl;
      float m = ls_cm[s * 64 + b];
      float hnew = (1.f - z) * n + z * hold1;
      float hout = (m > 0.5f) ? hnew : hold1;
      hold1 = hout;
      int oo = (((s + 1) * 2 + t1) * 64 + b) * 256 + hd1 + c;
      u16 xh, xl; split_bf16(hout, xh, xl);
      astore(hpk + oo, (u32)xh | ((u32)xl << 16));
    }
    ++epoch;
    bar_arrive(slots, blk, epoch);

    // ---- pre-poll local work: m2 (mWhh @ h_meta, regs) + gix prefetch ----
    f32x4 m1 = (f32x4){0.f, 0.f, 0.f, 0.f};
    f32x4 m2 = (f32x4){0.f, 0.f, 0.f, 0.f};
    if (s > 0) {
      #pragma unroll
      for (int k = 0; k < 8; ++k) {
        short8 bh = *(const short8*)(lw2h + (16 + k) * 512 + lane * 8);
        short8 bl = *(const short8*)(lw2l + (16 + k) * 512 + lane * 8);
        m2 = mfma16(ah1[k], bh, m2);
        m2 = mfma16(al1[k], bh, m2);
        m2 = mfma16(ah1[k], bl, m2);
      }
    }
    if (s < 29) {
      const float* grow = gix + (size_t)(blk * 30 + s + 1) * 2048;
      #pragma unroll
      for (int i = 0; i < 4; ++i) {
        int r = w * 16 + (lane >> 4) * 4 + i;
        gq[i]     = grow[r * 32 + cc];
        gq[4 + i] = grow[r * 32 + 16 + (cc & 7)];
      }
    }
    bar_wait(slots, epoch);
    if (blk == 0 && tid == 0) astore(hprog, (u32)epoch);

    // ---------- phase 2: meta GRU ----------
    {
      const u32* Hp = hpk + (size_t)(((s + 1) * 2 + t1) * 64 + arow) * 256 + ko;
      const u32* Hq = hpk + (size_t)(((s + 1) * 2 + (1 - t1)) * 64 + arow) * 256 + ko;
      uint4 rx[16], ry[16];
      #pragma unroll
      for (int k = 0; k < 8; ++k) {
        rx[2 * k]     = *(const uint4*)(Hp + k * 32);
        rx[2 * k + 1] = *(const uint4*)(Hp + k * 32 + 4);
        ry[2 * k]     = *(const uint4*)(Hq + k * 32);
        ry[2 * k + 1] = *(const uint4*)(Hq + k * 32 + 4);
      }
      #pragma unroll
      for (int k = 0; k < 8; ++k) {
        unpack8(rx[2 * k], rx[2 * k + 1], xh2[k], xl2[k]);
        short8 bh = *(const short8*)(lw2h + k * 512 + lane * 8);
        short8 bl = *(const short8*)(lw2l + k * 512 + lane * 8);
        m1 = mfma16(xh2[k], bh, m1);
        m1 = mfma16(xl2[k], bh, m1);
        m1 = mfma16(xh2[k], bl, m1);
      }
      #pragma unroll
      for (int k = 0; k < 8; ++k) {
        short8 yh, yl;
        unpack8(ry[2 * k], ry[2 * k + 1], yh, yl);
        short8 bh = *(const short8*)(lw2h + (8 + k) * 512 + lane * 8);
        short8 bl = *(const short8*)(lw2l + (8 + k) * 512 + lane * 8);
        m1 = mfma16(yh, bh, m1);
        m1 = mfma16(yl, bh, m1);
        m1 = mfma16(yh, bl, m1);
      }
    }
    #pragma unroll
    for (int i = 0; i < 4; ++i) {
      int rl = (lane >> 4) * 4 + i;
      if (cc < 8) {
        ls_rz[(w * 16 + rl) * 16 + cc] = m1[i] + m2[i] + mrz_b;
      } else if (cc < 12) {
        ls_gi[(w * 16 + rl) * 8 + (cc - 8)] = m1[i] + mgi_b;
        ls_gh[(w * 16 + rl) * 8 + (cc - 8)] = m2[i] + mgh_b;
      }
    }
    asm volatile("s_waitcnt lgkmcnt(0)" ::: "memory");
    {
      int rl = lane >> 2, c = lane & 3;
      float rv = ls_rz[(w * 16 + rl) * 16 + c], zv = ls_rz[(w * 16 + rl) * 16 + 4 + c];
      float gi = ls_gi[(w * 16 + rl) * 8 + c], gh = ls_gh[(w * 16 + rl) * 8 + c];
      float r = 1.f / (1.f + expf(-rv));
      float z = 1.f / (1.f + expf(-zv));
      float n = tanhf(gi + r * gh);
      int b = w * 16 + rl;
      int g2 = hd2 + c;
      float hmnew = (1.f - z) * n + z * hm_reg;
      hm_reg = hmnew;
      int ar = s * 64 + b;    // S-MAJOR
      u16 xh, xl; split_bf16(hmnew, xh, xl);
      astore(apk + ar * 256 + g2, (u32)xh | ((u32)xl << 16));
    }
    ++epoch;
    bar_arrive(slots, blk, epoch);

    // ---- pre-poll local work for next step: a2s = Whh @ h_task (regs) ----
    a2s[0] = (f32x4){0.f, 0.f, 0.f, 0.f};
    a2s[1] = (f32x4){0.f, 0.f, 0.f, 0.f};
    if (s < 29) {
      #pragma unroll
      for (int k = 0; k < 8; ++k) {
        #pragma unroll
        for (int nt = 0; nt < 2; ++nt) {
          short8 bh = *(const short8*)(lw1h + ((8 + k) * 2 + nt) * 512 + lane * 8);
          short8 bl = *(const short8*)(lw1l + ((8 + k) * 2 + nt) * 512 + lane * 8);
          a2s[nt] = mfma16(xh2[k], bh, a2s[nt]);
          a2s[nt] = mfma16(xl2[k], bh, a2s[nt]);
          a2s[nt] = mfma16(xh2[k], bl, a2s[nt]);
        }
      }
    }
  }
  // final: publish epoch 60 once all blocks have arrived (gnew q=14 waits on it)
  if (blk == 0) {
    bar_wait(slots, epoch);
    if (tid == 0) astore(hprog, (u32)epoch);
  }
}

extern "C" void kernel_launch(void* const* d_in, const int* in_sizes, int n_in,
                              void* d_out, int out_size, void* d_ws, size_t ws_size,
                              hipStream_t stream) {
  const int* iv = (const int*)d_in[1];
  const int* cv = (const int*)d_in[2];
  const float* emb = (const float*)d_in[3];
  const float* Wih = (const float*)d_in[4];
  const float* Whh = (const float*)d_in[5];
  const float* bih = (const float*)d_in[6];
  const float* bhh = (const float*)d_in[7];
  const float* mWih = (const float*)d_in[8];
  const float* mWhh = (const float*)d_in[9];
  const float* mbih = (const float*)d_in[10];
  const float* mbhh = (const float*)d_in[11];
  const float* Wnew = (const float*)d_in[12];
  const float* bnew = (const float*)d_in[13];
  const float* Wcopy = (const float*)d_in[14];
  const float* bcopy = (const float*)d_in[15];
  float* out = (float*)d_out;
  char* ws = (char*)d_ws;

  size_t o = 0;
  auto take = [&](size_t sz) { size_t r = o; o += sz; return r; };
  size_t BAR = take(512);        // [0..63] rnn flags, [64] hprog (own line)
  size_t CM  = take(15360);
  size_t EBH = take(983040);
  size_t EBL = take(983040);
  size_t HPK = take(4063232);    // packed bf16 hi|lo task-h [31][2][64][256] u32
  size_t APK = take(1966080);    // packed bf16 hi|lo meta-h [30][64][256] u32 (s-major)
  size_t GIX = take(15728640);   // fp32 gi_x [64 blk][30][64][32]
  size_t W1H = take(2621440);
  size_t W1L = take(2621440);
  size_t W2H = take(1572864);
  size_t W2L = take(1572864);
  size_t WNH = take(10289152);
  size_t WNL = take(10289152);
  if (ws_size < o) return;   // insufficient workspace: fail loudly via absmax

  hipFuncSetAttribute(reinterpret_cast<const void*>(k_mega),
                      hipFuncAttributeMaxDynamicSharedMemorySize, RNN_LDS);

  hipMemsetAsync(ws + BAR, 0, 512, stream);

  k_prep<<<5456, 256, 0, stream>>>(iv, emb, (u16*)(ws + EBH), (u16*)(ws + EBL), (float*)(ws + CM),
                                   Wih, Whh, mWih, mWhh, Wnew,
                                   (u16*)(ws + W1H), (u16*)(ws + W1L),
                                   (u16*)(ws + W2H), (u16*)(ws + W2L),
                                   (u16*)(ws + WNH), (u16*)(ws + WNL));
  k_gix<<<64, 256, 0, stream>>>((const u16*)(ws + EBH), (const u16*)(ws + EBL),
                                (const u16*)(ws + W1H), (const u16*)(ws + W1L),
                                bih, bhh, (float*)(ws + GIX));
  k_mega<<<NB_ + NHELP_, 256, RNN_LDS, stream>>>(
      (const u16*)(ws + W1H), (const u16*)(ws + W1L),
      (const u16*)(ws + W2H), (const u16*)(ws + W2L),
      (const float*)(ws + GIX), bhh, mbih, mbhh,
      (const float*)(ws + CM),
      (u32*)(ws + HPK), (u32*)(ws + APK),
      (u32*)(ws + BAR),
      (const u16*)(ws + WNH), (const u16*)(ws + WNL),
      bnew, cv, Wcopy, bcopy, out);
}